// Round 1
// 490.640 us; speedup vs baseline: 1.0097x; 1.0097x over previous
//
#include <hip/hip_runtime.h>

#define B_ 1024
#define T_ 200
#define H_ 128

typedef __attribute__((ext_vector_type(8))) short short8;
typedef __attribute__((ext_vector_type(4))) float f32x4;

#define MFMA(a, b, c) __builtin_amdgcn_mfma_f32_16x16x32_bf16((a), (b), (c), 0, 0, 0)

static __device__ __forceinline__ short f2bf(float f) {
  unsigned u = __float_as_uint(f);
  u += 0x7fffu + ((u >> 16) & 1u);  // RNE
  return (short)(u >> 16);
}
static __device__ __forceinline__ float bf2f(short s) {
  return __uint_as_float(((unsigned)(unsigned short)s) << 16);
}
// pack two floats as bf16 (RNE) into one dword: low short = a, high short = b
static __device__ __forceinline__ unsigned pack2bf_rne(float a, float b) {
  unsigned ua = __float_as_uint(a);
  ua += 0x7fffu + ((ua >> 16) & 1u);
  unsigned ub = __float_as_uint(b);
  ub += 0x7fffu + ((ub >> 16) & 1u);
  return (ua >> 16) | (ub & 0xFFFF0000u);
}
// truncating pack (matches previous h-state rounding)
static __device__ __forceinline__ unsigned pack2bf_trunc(float a, float b) {
  return (__float_as_uint(a) >> 16) | (__float_as_uint(b) & 0xFFFF0000u);
}
static __device__ __forceinline__ float rcp_f(float x) { return __builtin_amdgcn_rcpf(x); }
// CK-style barrier: LDS-only drain, does NOT drain vmcnt (keeps global prefetch alive)
static __device__ __forceinline__ void ck_barrier() {
  asm volatile("s_waitcnt lgkmcnt(0)\n\ts_barrier" ::: "memory");
}

// ---------------------------------------------------------------------------
// K_A: attention scores (split bf16 3-pass, fp32-grade) + hist->bf16 repack
// into scan-native B-fragment-direct global layout.
// SWAPPED MFMA OPERANDS: A = weight frags, B = tgt frags. D is transposed:
// lane holds (batch row n = lane&15) x (4 consecutive cols w*16+q*4..+3).
// Lets the hist-dot use one b128 LDS read + 4 FMA + 2 shfl (was 4 scalar
// reads + 4 shfl). Fragment packing / LDS layouts unchanged vs previous rev.
// histbf layout (shorts): ((bb*200+t)*4 + ks)*512 + wl*8 + j
//   holds hist[row=bb*16+(wl&15)][k=ks*32+(wl>>4)*8+j], wl = wave-lane 0..63.
// ---------------------------------------------------------------------------
__global__ __launch_bounds__(512, 1) void proj_scores_kernel(
    const float* __restrict__ tgt, const float* __restrict__ hist,
    const float* __restrict__ Ww, const float* __restrict__ Wb,
    float* __restrict__ scores, short* __restrict__ histbf) {
  const int tc = blockIdx.x, bb = blockIdx.y;
  const int nt = (tc == 12) ? 8 : 16;
  const int t0 = tc * 16;
  const int tid = threadIdx.x;
  const int lane = tid & 63, w = tid >> 6;
  const int n = lane & 15, q = lane >> 4;

  __shared__ short tgt_hi[2][16 * 128];
  __shared__ short tgt_lo[2][16 * 128];
  __shared__ float hist_f[2][16 * 132];  // padded rows
  __shared__ float sp[16 * 8];

  // register A-frags for Ww (hi/lo split): A[i][k] = Ww[w*16+i][k]
  short8 whi[4], wlo[4];
  f32x4 wb4;
  {
    const int o = w * 16 + n;
#pragma unroll
    for (int ks = 0; ks < 4; ++ks) {
      const float* p = Ww + o * H_ + ks * 32 + q * 8;
      short8 h, l;
#pragma unroll
      for (int j = 0; j < 8; ++j) {
        float f = p[j];
        short hv = f2bf(f);
        h[j] = hv;
        l[j] = f2bf(f - bf2f(hv));
      }
      whi[ks] = h;
      wlo[ks] = l;
    }
    wb4 = *(const f32x4*)(Wb + w * 16 + q * 4);  // biases for this lane's 4 cols
  }

  // staging: thread -> (row sm, 4-float granule cs)
  const int sm = tid >> 5, cs = tid & 31;
  const int g = cs >> 1, half = cs & 1;
  const int spos16 = sm * 128 + ((g ^ (sm & 7)) * 8) + half * 4;  // shorts
  const int sposf = sm * 132 + cs * 4;                            // floats
  const size_t rowbase = ((size_t)(bb * 16 + sm) * T_) * H_ + cs * 4;

  // histbf conversion mapping: thread handles 8 bytes (4 shorts)
  const int cu = tid;
  const int cks = cu >> 7, crem = cu & 127, cwl = crem >> 1, chalf = crem & 1;
  const int crow = cwl & 15, ckb = cks * 32 + (cwl >> 4) * 8 + chalf * 4;

  float4 hv = *(const float4*)(hist + rowbase + (size_t)t0 * H_);
  float4 tv = *(const float4*)(tgt + rowbase + (size_t)t0 * H_);
  {
    *(float4*)&hist_f[0][sposf] = hv;
    uint2 hi, lo;
    hi.x = pack2bf_rne(tv.x, tv.y);
    hi.y = pack2bf_rne(tv.z, tv.w);
    lo.x = pack2bf_rne(tv.x - bf2f((short)(hi.x)), tv.y - bf2f((short)(hi.x >> 16)));
    lo.y = pack2bf_rne(tv.z - bf2f((short)(hi.y)), tv.w - bf2f((short)(hi.y >> 16)));
    *(uint2*)&tgt_hi[0][spos16] = hi;
    *(uint2*)&tgt_lo[0][spos16] = lo;
  }
  ck_barrier();

  for (int tl = 0; tl < nt; ++tl) {
    const int cur = tl & 1, nxt = cur ^ 1;
    const bool have_next = (tl + 1 < nt);
    if (have_next) {
      hv = *(const float4*)(hist + rowbase + (size_t)(t0 + tl + 1) * H_);
      tv = *(const float4*)(tgt + rowbase + (size_t)(t0 + tl + 1) * H_);
    }
    // scores MFMA: 3-pass split bf16, swapped operands (A = W, B = tgt)
    f32x4 s1 = {0, 0, 0, 0}, s2 = {0, 0, 0, 0}, s3 = {0, 0, 0, 0};
#pragma unroll
    for (int ks = 0; ks < 4; ++ks) {
      const int fp = n * 128 + ((ks * 4 + q) ^ (n & 7)) * 8;
      short8 ahi = *(short8*)&tgt_hi[cur][fp];
      short8 alo = *(short8*)&tgt_lo[cur][fp];
      s1 = MFMA(whi[ks], ahi, s1);
      s2 = MFMA(wlo[ks], ahi, s2);
      s3 = MFMA(whi[ks], alo, s3);
    }
    // dot with hist (fp32): lane holds (row n, cols w*16+q*4..+3)
    {
      f32x4 hv4 = *(const f32x4*)&hist_f[cur][n * 132 + w * 16 + q * 4];
      float v = (s1[0] + s2[0] + s3[0] + wb4[0]) * hv4[0];
      v += (s1[1] + s2[1] + s3[1] + wb4[1]) * hv4[1];
      v += (s1[2] + s2[2] + s3[2] + wb4[2]) * hv4[2];
      v += (s1[3] + s2[3] + s3[3] + wb4[3]) * hv4[3];
      v += __shfl_xor(v, 16);
      v += __shfl_xor(v, 32);
      if (lane < 16) sp[n * 8 + w] = v;
    }
    // hist -> bf16 packed global (scan-native layout), once per element
    if (histbf != nullptr) {
      const float* src = &hist_f[cur][crow * 132 + ckb];
      uint2 u;
      u.x = pack2bf_rne(src[0], src[1]);
      u.y = pack2bf_rne(src[2], src[3]);
      const size_t sb = (((size_t)(bb * T_ + t0 + tl) * 4) + cks) * 512 + cwl * 8 + chalf * 4;
      *(uint2*)(histbf + sb) = u;
    }
    // stage next tile (prefetched regs)
    if (have_next) {
      *(float4*)&hist_f[nxt][sposf] = hv;
      uint2 hi, lo;
      hi.x = pack2bf_rne(tv.x, tv.y);
      hi.y = pack2bf_rne(tv.z, tv.w);
      lo.x = pack2bf_rne(tv.x - bf2f((short)(hi.x)), tv.y - bf2f((short)(hi.x >> 16)));
      lo.y = pack2bf_rne(tv.z - bf2f((short)(hi.y)), tv.w - bf2f((short)(hi.y >> 16)));
      *(uint2*)&tgt_hi[nxt][spos16] = hi;
      *(uint2*)&tgt_lo[nxt][spos16] = lo;
    }
    ck_barrier();
    if (tid < 16) {
      float s = 0.0f;
#pragma unroll
      for (int ww = 0; ww < 8; ++ww) s += sp[tid * 8 + ww];
      scores[(size_t)(bb * 16 + tid) * T_ + (t0 + tl)] = s;
    }
    ck_barrier();
  }
}

// ---------------------------------------------------------------------------
// K_B: softmax over T, in place. One block per batch row.
// ---------------------------------------------------------------------------
__global__ __launch_bounds__(256, 4) void softmax_kernel(float* __restrict__ att) {
  const int b = blockIdx.x, tid = threadIdx.x;
  const int lane = tid & 63, wave = tid >> 6;
  __shared__ float red[8];
  float v = (tid < T_) ? att[(size_t)b * T_ + tid] : -3.0e38f;
  float mx = v;
#pragma unroll
  for (int d = 1; d < 64; d <<= 1) mx = fmaxf(mx, __shfl_xor(mx, d));
  if (lane == 0) red[wave] = mx;
  __syncthreads();
  mx = fmaxf(fmaxf(red[0], red[1]), fmaxf(red[2], red[3]));
  float e = (tid < T_) ? __expf(v - mx) : 0.0f;
  float sm = e;
#pragma unroll
  for (int d = 1; d < 64; d <<= 1) sm += __shfl_xor(sm, d);
  if (lane == 0) red[4 + wave] = sm;
  __syncthreads();
  sm = red[4] + red[5] + red[6] + red[7];
  if (tid < T_) att[(size_t)b * T_ + tid] = e / sm;
}

// ---------------------------------------------------------------------------
// K_C: recurrent scan v4. 64 blocks x 16 rows, 512 threads (8 waves, wave w =
// coltile w). SWAPPED MFMA OPERANDS: A = weight frags (identical packing to
// v3), B = h/x frags (identical LDS/global layout + swizzle to v3). D is
// transposed: lane holds (batch row n) x (4 consecutive cols ob..ob+3), so
//   - h write-back is ONE ds_write_b64 per lane (was 4 row-strided b16s):
//     8 wave-write-instrs/CU-step instead of 32, <=2-way banked (free).
//   - att is per-row: 1 prefetched load per lane/step (was 4).
//   - h_out final store is one dwordx4.
// x-side MFMAs (register inputs, no lgkm dep) are issued BEFORE h-side MFMAs
// to cover the post-barrier ds_read_b128 latency.
// Gates use v_rcp/v_exp only. One lgkm-only barrier/step.
// ---------------------------------------------------------------------------
template <bool DIRECT>
__global__ __launch_bounds__(512, 2) void scan3_kernel(
    const float* __restrict__ hist,
    const float* __restrict__ xu_w, const float* __restrict__ xu_b,
    const float* __restrict__ hu_w, const float* __restrict__ hu_b,
    const float* __restrict__ xr_w, const float* __restrict__ xr_b,
    const float* __restrict__ hr_w, const float* __restrict__ hr_b,
    const float* __restrict__ xg_w, const float* __restrict__ xg_b,
    const float* __restrict__ hg_w, const float* __restrict__ hg_b,
    const float* __restrict__ att, const short* __restrict__ histbf,
    float* __restrict__ h_out) {
  const int tid = threadIdx.x;
  const int lane = tid & 63, w = tid >> 6;
  const int n = lane & 15, q = lane >> 4;
  const int bb = blockIdx.x, r0 = bb * 16;
  const int o = w * 16 + n;       // A-frag packing index (W rows = output cols)
  const int ob = w * 16 + q * 4;  // this lane's 4 output cols (D layout)

  __shared__ short hbuf[2][16 * 128];
  __shared__ short xbuf[2][16 * 128];  // only used when !DIRECT

  // A-frags: 0=xu 1=hu 2=xr 3=hr 4=xg 5=hg  (96 VGPRs)
  short8 wf[6][4];
  {
    const float* Wm[6] = {xu_w, hu_w, xr_w, hr_w, xg_w, hg_w};
#pragma unroll
    for (int M = 0; M < 6; ++M)
#pragma unroll
      for (int ks = 0; ks < 4; ++ks) {
        const float* p = Wm[M] + o * H_ + ks * 32 + q * 8;
        short8 v;
#pragma unroll
        for (int j = 0; j < 8; ++j) v[j] = f2bf(p[j]);
        wf[M][ks] = v;
      }
  }
  // biases for this lane's 4 output cols (f32x4, 16B-aligned: ob % 4 == 0)
  const f32x4 bu4 = *(const f32x4*)(xu_b + ob) + *(const f32x4*)(hu_b + ob);
  const f32x4 br4 = *(const f32x4*)(xr_b + ob) + *(const f32x4*)(hr_b + ob);
  const f32x4 bxg4 = *(const f32x4*)(xg_b + ob);
  const f32x4 bhg4 = *(const f32x4*)(hg_b + ob);

  for (int i = tid; i < 16 * 128; i += 512) hbuf[0][i] = 0;

  // --- x-fragment prefetch state ---
  typedef union { uint4 u; short8 s; } frag_u;
  frag_u xp[2][4];
  const short* px = histbf + ((size_t)bb * T_ * 4) * 512 + (size_t)lane * 8;
  // --- fallback staging state ---
  const int sm = tid >> 5, cs = tid & 31;
  const int xpos = sm * 128 + (((cs >> 1) ^ (sm & 7)) * 8) + (cs & 1) * 4;
  const float* hrow = hist + ((size_t)(r0 + sm) * T_) * H_ + cs * 4;
  float4 xnext;

  if constexpr (DIRECT) {
#pragma unroll
    for (int s = 0; s < 2; ++s)
#pragma unroll
      for (int ks = 0; ks < 4; ++ks)
        xp[s][ks].u = *(const uint4*)(px + (size_t)(s * 4 + ks) * 512);
  } else {
    float4 a = *(const float4*)hrow;  // x(0)
    uint2 u;
    u.x = pack2bf_rne(a.x, a.y);
    u.y = pack2bf_rne(a.z, a.w);
    *(uint2*)&xbuf[0][xpos] = u;
    xnext = *(const float4*)(hrow + H_);  // x(1)
  }

  // att prefetch (depth 2): one value per lane (its batch row n), L1-resident
  float ap2[2];
  const float* pa = att + (size_t)(r0 + n) * T_;
  ap2[0] = pa[0];
  ap2[1] = pa[1];

  // this lane's h state: h[row n][cols ob..ob+3]
  float hreg[4] = {0.0f, 0.0f, 0.0f, 0.0f};
  // h write-back address: 4 consecutive cols inside one swizzle granule
  const int wri = n * 128 + (((w * 2 + (q >> 1)) ^ (n & 7)) * 8) + (q & 1) * 4;
  ck_barrier();

#pragma unroll 2
  for (int t = 0; t < T_; ++t) {
    const int cur = t & 1, nxt = cur ^ 1;
    short8 ha[4];
#pragma unroll
    for (int ks = 0; ks < 4; ++ks)
      ha[ks] = *(short8*)&hbuf[cur][n * 128 + ((ks * 4 + q) ^ (n & 7)) * 8];
    short8 xa[4];
    if constexpr (DIRECT) {
#pragma unroll
      for (int ks = 0; ks < 4; ++ks) xa[ks] = xp[cur][ks].s;
    } else {
#pragma unroll
      for (int ks = 0; ks < 4; ++ks)
        xa[ks] = *(short8*)&xbuf[cur][n * 128 + ((ks * 4 + q) ^ (n & 7)) * 8];
    }
    f32x4 axu = {0, 0, 0, 0}, ahu = {0, 0, 0, 0}, axr = {0, 0, 0, 0},
          ahr = {0, 0, 0, 0}, axg = {0, 0, 0, 0}, ahg = {0, 0, 0, 0};
    // x-side first: register-only inputs, no lgkm dependency — covers the
    // latency of the ds_reads issued above.
#pragma unroll
    for (int ks = 0; ks < 4; ++ks) {
      axu = MFMA(wf[0][ks], xa[ks], axu);
      axr = MFMA(wf[2][ks], xa[ks], axr);
      axg = MFMA(wf[4][ks], xa[ks], axg);
    }
#pragma unroll
    for (int ks = 0; ks < 4; ++ks) {
      ahu = MFMA(wf[1][ks], ha[ks], ahu);
      ahr = MFMA(wf[3][ks], ha[ks], ahr);
      ahg = MFMA(wf[5][ks], ha[ks], ahg);
    }
    // issue prefetches for t+2 (vmcnt NOT drained by ck_barrier)
    const int tp = (t + 2 < T_) ? t + 2 : T_ - 1;
    if constexpr (DIRECT) {
#pragma unroll
      for (int ks = 0; ks < 4; ++ks)
        xp[cur][ks].u = *(const uint4*)(px + (size_t)(tp * 4 + ks) * 512);
    } else {
      uint2 u;
      u.x = pack2bf_rne(xnext.x, xnext.y);
      u.y = pack2bf_rne(xnext.z, xnext.w);
      *(uint2*)&xbuf[nxt][xpos] = u;  // stage x(t+1)
      xnext = *(const float4*)(hrow + (size_t)tp * H_);
    }
    const float at = ap2[cur];
    ap2[cur] = pa[tp];
    // gates + h update (rcp-based, no IEEE division); one att value (row n)
    float hn[4];
#pragma unroll
    for (int r = 0; r < 4; ++r) {
      const float su = axu[r] + ahu[r] + bu4[r];
      const float u = at * rcp_f(1.0f + __expf(-su));
      const float sr = axr[r] + ahr[r] + br4[r];
      const float rr = rcp_f(1.0f + __expf(-sr));
      const float sg = (axg[r] + bxg4[r]) + rr * (ahg[r] + bhg4[r]);
      const float g = 2.0f * rcp_f(1.0f + __expf(-2.0f * sg)) - 1.0f;
      hn[r] = hreg[r] + u * (g - hreg[r]);
      hreg[r] = hn[r];
    }
    // single 8B LDS write: 4 consecutive bf16 cols of row n
    uint2 up;
    up.x = pack2bf_trunc(hn[0], hn[1]);
    up.y = pack2bf_trunc(hn[2], hn[3]);
    *(uint2*)&hbuf[nxt][wri] = up;
    if (t == T_ - 1) {
      f32x4 hv = {hn[0], hn[1], hn[2], hn[3]};
      *(f32x4*)(h_out + (size_t)(r0 + n) * H_ + ob) = hv;
    }
    ck_barrier();
  }
}

// ---------------------------------------------------------------------------
// K_D: out = [h | targets[:,0]] @ ln2_w^T + ln2_b (fp32)
// ---------------------------------------------------------------------------
__global__ __launch_bounds__(256, 4) void final_kernel(
    const float* __restrict__ tgt, const float* __restrict__ hfin,
    const float* __restrict__ w, const float* __restrict__ bias,
    float* __restrict__ out) {
  const int b = blockIdx.x, tid = threadIdx.x;
  const int o = tid >> 1, half = tid & 1;
  const float* src = half ? (tgt + (size_t)b * (T_ * H_)) : (hfin + (size_t)b * H_);
  const float* wrow = w + o * 256 + half * 128;
  float acc = 0.0f;
#pragma unroll 8
  for (int k = 0; k < 128; k += 4) {
    float4 sv = *(const float4*)(src + k);
    float4 wv = *(const float4*)(wrow + k);
    acc += sv.x * wv.x + sv.y * wv.y + sv.z * wv.z + sv.w * wv.w;
  }
  acc += __shfl_xor(acc, 1);
  if (half == 0) out[(size_t)b * H_ + o] = acc + bias[o];
}

extern "C" void kernel_launch(void* const* d_in, const int* in_sizes, int n_in,
                              void* d_out, int out_size, void* d_ws, size_t ws_size,
                              hipStream_t stream) {
  const float* targets = (const float*)d_in[0];
  const float* history = (const float*)d_in[1];
  const float* W_w = (const float*)d_in[2];
  const float* W_b = (const float*)d_in[3];
  const float* xu_w = (const float*)d_in[4];
  const float* xu_b = (const float*)d_in[5];
  const float* hu_w = (const float*)d_in[6];
  const float* hu_b = (const float*)d_in[7];
  const float* xr_w = (const float*)d_in[8];
  const float* xr_b = (const float*)d_in[9];
  const float* hr_w = (const float*)d_in[10];
  const float* hr_b = (const float*)d_in[11];
  const float* xg_w = (const float*)d_in[12];
  const float* xg_b = (const float*)d_in[13];
  const float* hg_w = (const float*)d_in[14];
  const float* hg_b = (const float*)d_in[15];
  const float* ln2_w = (const float*)d_in[16];
  const float* ln2_b = (const float*)d_in[17];
  float* out = (float*)d_out;

  float* att = (float*)d_ws;            // [B,T] f32
  float* hfin = att + (size_t)B_ * T_;  // [B,H] f32
  const size_t fixed = (size_t)B_ * T_ * 4 + (size_t)B_ * H_ * 4;
  const size_t histbf_bytes = (size_t)64 * T_ * 4 * 512 * 8 * 2;  // 52.4 MB
  short* histbf = (ws_size >= fixed + histbf_bytes)
                      ? (short*)((char*)d_ws + fixed)
                      : nullptr;

  proj_scores_kernel<<<dim3(13, 64), dim3(512), 0, stream>>>(
      targets, history, W_w, W_b, att, histbf);
  softmax_kernel<<<dim3(B_), dim3(256), 0, stream>>>(att);
  if (histbf) {
    scan3_kernel<true><<<dim3(64), dim3(512), 0, stream>>>(
        history, xu_w, xu_b, hu_w, hu_b, xr_w, xr_b, hr_w, hr_b,
        xg_w, xg_b, hg_w, hg_b, att, histbf, hfin);
  } else {
    scan3_kernel<false><<<dim3(64), dim3(512), 0, stream>>>(
        history, xu_w, xu_b, hu_w, hu_b, xr_w, xr_b, hr_w, hr_b,
        xg_w, xg_b, hg_w, hg_b, att, histbf, hfin);
  }
  final_kernel<<<dim3(B_), dim3(256), 0, stream>>>(targets, hfin, ln2_w, ln2_b, out);
}

// Round 2
// 471.381 us; speedup vs baseline: 1.0509x; 1.0409x over previous
//
#include <hip/hip_runtime.h>

#define B_ 1024
#define T_ 200
#define H_ 128

typedef __attribute__((ext_vector_type(8))) short short8;
typedef __attribute__((ext_vector_type(4))) float f32x4;

#define MFMA(a, b, c) __builtin_amdgcn_mfma_f32_16x16x32_bf16((a), (b), (c), 0, 0, 0)

static __device__ __forceinline__ short f2bf(float f) {
  unsigned u = __float_as_uint(f);
  u += 0x7fffu + ((u >> 16) & 1u);  // RNE
  return (short)(u >> 16);
}
static __device__ __forceinline__ float bf2f(short s) {
  return __uint_as_float(((unsigned)(unsigned short)s) << 16);
}
// pack two floats as bf16 (RNE) into one dword: low short = a, high short = b
static __device__ __forceinline__ unsigned pack2bf_rne(float a, float b) {
  unsigned ua = __float_as_uint(a);
  ua += 0x7fffu + ((ua >> 16) & 1u);
  unsigned ub = __float_as_uint(b);
  ub += 0x7fffu + ((ub >> 16) & 1u);
  return (ua >> 16) | (ub & 0xFFFF0000u);
}
// truncating pack (matches previous h-state rounding)
static __device__ __forceinline__ unsigned pack2bf_trunc(float a, float b) {
  return (__float_as_uint(a) >> 16) | (__float_as_uint(b) & 0xFFFF0000u);
}
static __device__ __forceinline__ float rcp_f(float x) { return __builtin_amdgcn_rcpf(x); }
// CK-style barrier: LDS-only drain, does NOT drain vmcnt (keeps global prefetch alive)
static __device__ __forceinline__ void ck_barrier() {
  asm volatile("s_waitcnt lgkmcnt(0)\n\ts_barrier" ::: "memory");
}

// ---------------------------------------------------------------------------
// K_A: attention scores (split bf16 3-pass, fp32-grade) + hist->bf16 repack
// into scan-native B-fragment-direct global layout. (unchanged from prev rev)
// ---------------------------------------------------------------------------
__global__ __launch_bounds__(512, 1) void proj_scores_kernel(
    const float* __restrict__ tgt, const float* __restrict__ hist,
    const float* __restrict__ Ww, const float* __restrict__ Wb,
    float* __restrict__ scores, short* __restrict__ histbf) {
  const int tc = blockIdx.x, bb = blockIdx.y;
  const int nt = (tc == 12) ? 8 : 16;
  const int t0 = tc * 16;
  const int tid = threadIdx.x;
  const int lane = tid & 63, w = tid >> 6;
  const int n = lane & 15, q = lane >> 4;

  __shared__ short tgt_hi[2][16 * 128];
  __shared__ short tgt_lo[2][16 * 128];
  __shared__ float hist_f[2][16 * 132];  // padded rows
  __shared__ float sp[16 * 8];

  // register A-frags for Ww (hi/lo split): A[i][k] = Ww[w*16+i][k]
  short8 whi[4], wlo[4];
  f32x4 wb4;
  {
    const int o = w * 16 + n;
#pragma unroll
    for (int ks = 0; ks < 4; ++ks) {
      const float* p = Ww + o * H_ + ks * 32 + q * 8;
      short8 h, l;
#pragma unroll
      for (int j = 0; j < 8; ++j) {
        float f = p[j];
        short hv = f2bf(f);
        h[j] = hv;
        l[j] = f2bf(f - bf2f(hv));
      }
      whi[ks] = h;
      wlo[ks] = l;
    }
    wb4 = *(const f32x4*)(Wb + w * 16 + q * 4);  // biases for this lane's 4 cols
  }

  // staging: thread -> (row sm, 4-float granule cs)
  const int sm = tid >> 5, cs = tid & 31;
  const int g = cs >> 1, half = cs & 1;
  const int spos16 = sm * 128 + ((g ^ (sm & 7)) * 8) + half * 4;  // shorts
  const int sposf = sm * 132 + cs * 4;                            // floats
  const size_t rowbase = ((size_t)(bb * 16 + sm) * T_) * H_ + cs * 4;

  // histbf conversion mapping: thread handles 8 bytes (4 shorts)
  const int cu = tid;
  const int cks = cu >> 7, crem = cu & 127, cwl = crem >> 1, chalf = crem & 1;
  const int crow = cwl & 15, ckb = cks * 32 + (cwl >> 4) * 8 + chalf * 4;

  float4 hv = *(const float4*)(hist + rowbase + (size_t)t0 * H_);
  float4 tv = *(const float4*)(tgt + rowbase + (size_t)t0 * H_);
  {
    *(float4*)&hist_f[0][sposf] = hv;
    uint2 hi, lo;
    hi.x = pack2bf_rne(tv.x, tv.y);
    hi.y = pack2bf_rne(tv.z, tv.w);
    lo.x = pack2bf_rne(tv.x - bf2f((short)(hi.x)), tv.y - bf2f((short)(hi.x >> 16)));
    lo.y = pack2bf_rne(tv.z - bf2f((short)(hi.y)), tv.w - bf2f((short)(hi.y >> 16)));
    *(uint2*)&tgt_hi[0][spos16] = hi;
    *(uint2*)&tgt_lo[0][spos16] = lo;
  }
  ck_barrier();

  for (int tl = 0; tl < nt; ++tl) {
    const int cur = tl & 1, nxt = cur ^ 1;
    const bool have_next = (tl + 1 < nt);
    if (have_next) {
      hv = *(const float4*)(hist + rowbase + (size_t)(t0 + tl + 1) * H_);
      tv = *(const float4*)(tgt + rowbase + (size_t)(t0 + tl + 1) * H_);
    }
    // scores MFMA: 3-pass split bf16, swapped operands (A = W, B = tgt)
    f32x4 s1 = {0, 0, 0, 0}, s2 = {0, 0, 0, 0}, s3 = {0, 0, 0, 0};
#pragma unroll
    for (int ks = 0; ks < 4; ++ks) {
      const int fp = n * 128 + ((ks * 4 + q) ^ (n & 7)) * 8;
      short8 ahi = *(short8*)&tgt_hi[cur][fp];
      short8 alo = *(short8*)&tgt_lo[cur][fp];
      s1 = MFMA(whi[ks], ahi, s1);
      s2 = MFMA(wlo[ks], ahi, s2);
      s3 = MFMA(whi[ks], alo, s3);
    }
    // dot with hist (fp32): lane holds (row n, cols w*16+q*4..+3)
    {
      f32x4 hv4 = *(const f32x4*)&hist_f[cur][n * 132 + w * 16 + q * 4];
      float v = (s1[0] + s2[0] + s3[0] + wb4[0]) * hv4[0];
      v += (s1[1] + s2[1] + s3[1] + wb4[1]) * hv4[1];
      v += (s1[2] + s2[2] + s3[2] + wb4[2]) * hv4[2];
      v += (s1[3] + s2[3] + s3[3] + wb4[3]) * hv4[3];
      v += __shfl_xor(v, 16);
      v += __shfl_xor(v, 32);
      if (lane < 16) sp[n * 8 + w] = v;
    }
    // hist -> bf16 packed global (scan-native layout), once per element
    if (histbf != nullptr) {
      const float* src = &hist_f[cur][crow * 132 + ckb];
      uint2 u;
      u.x = pack2bf_rne(src[0], src[1]);
      u.y = pack2bf_rne(src[2], src[3]);
      const size_t sb = (((size_t)(bb * T_ + t0 + tl) * 4) + cks) * 512 + cwl * 8 + chalf * 4;
      *(uint2*)(histbf + sb) = u;
    }
    // stage next tile (prefetched regs)
    if (have_next) {
      *(float4*)&hist_f[nxt][sposf] = hv;
      uint2 hi, lo;
      hi.x = pack2bf_rne(tv.x, tv.y);
      hi.y = pack2bf_rne(tv.z, tv.w);
      lo.x = pack2bf_rne(tv.x - bf2f((short)(hi.x)), tv.y - bf2f((short)(hi.x >> 16)));
      lo.y = pack2bf_rne(tv.z - bf2f((short)(hi.y)), tv.w - bf2f((short)(hi.y >> 16)));
      *(uint2*)&tgt_hi[nxt][spos16] = hi;
      *(uint2*)&tgt_lo[nxt][spos16] = lo;
    }
    ck_barrier();
    if (tid < 16) {
      float s = 0.0f;
#pragma unroll
      for (int ww = 0; ww < 8; ++ww) s += sp[tid * 8 + ww];
      scores[(size_t)(bb * 16 + tid) * T_ + (t0 + tl)] = s;
    }
    ck_barrier();
  }
}

// ---------------------------------------------------------------------------
// K_B: softmax over T, in place. One block per batch row.
// ---------------------------------------------------------------------------
__global__ __launch_bounds__(256, 4) void softmax_kernel(float* __restrict__ att) {
  const int b = blockIdx.x, tid = threadIdx.x;
  const int lane = tid & 63, wave = tid >> 6;
  __shared__ float red[8];
  float v = (tid < T_) ? att[(size_t)b * T_ + tid] : -3.0e38f;
  float mx = v;
#pragma unroll
  for (int d = 1; d < 64; d <<= 1) mx = fmaxf(mx, __shfl_xor(mx, d));
  if (lane == 0) red[wave] = mx;
  __syncthreads();
  mx = fmaxf(fmaxf(red[0], red[1]), fmaxf(red[2], red[3]));
  float e = (tid < T_) ? __expf(v - mx) : 0.0f;
  float sm = e;
#pragma unroll
  for (int d = 1; d < 64; d <<= 1) sm += __shfl_xor(sm, d);
  if (lane == 0) red[4 + wave] = sm;
  __syncthreads();
  sm = red[4] + red[5] + red[6] + red[7];
  if (tid < T_) att[(size_t)b * T_ + tid] = e / sm;
}

// ---------------------------------------------------------------------------
// K_C: recurrent scan v5. 64 blocks x 16 rows, 512 threads (8 waves, wave w =
// coltile w). SOFTWARE-PIPELINED x-side: the 12 x-MFMAs for step t+1 are
// issued during step t, so their matrix-pipe time hides under step t's gate
// VALU (previously [24-MFMA cluster]->[gate cluster] serialized per step in
// barrier lockstep: ~930 + ~830 cyc/SIMD). Only the 12 h-side MFMAs remain on
// the recurrence path. x-accumulators are bias-seeded (C-in = bias).
// launch_bounds (512,1): grid=64 blocks on 256 CUs -> never 2 blocks/CU, so
// the old 128-VGPR cap only caused pressure; relax it for pipeline state.
// D-layout: lane holds (batch row n) x (4 consecutive cols ob..ob+3).
// ---------------------------------------------------------------------------
template <bool DIRECT>
__global__ __launch_bounds__(512, 1) void scan3_kernel(
    const float* __restrict__ hist,
    const float* __restrict__ xu_w, const float* __restrict__ xu_b,
    const float* __restrict__ hu_w, const float* __restrict__ hu_b,
    const float* __restrict__ xr_w, const float* __restrict__ xr_b,
    const float* __restrict__ hr_w, const float* __restrict__ hr_b,
    const float* __restrict__ xg_w, const float* __restrict__ xg_b,
    const float* __restrict__ hg_w, const float* __restrict__ hg_b,
    const float* __restrict__ att, const short* __restrict__ histbf,
    float* __restrict__ h_out) {
  const int tid = threadIdx.x;
  const int lane = tid & 63, w = tid >> 6;
  const int n = lane & 15, q = lane >> 4;
  const int bb = blockIdx.x, r0 = bb * 16;
  const int o = w * 16 + n;       // A-frag packing index (W rows = output cols)
  const int ob = w * 16 + q * 4;  // this lane's 4 output cols (D layout)

  __shared__ short hbuf[2][16 * 128];
  __shared__ short xbuf[2][16 * 128];  // only used when !DIRECT

  // A-frags: 0=xu 1=hu 2=xr 3=hr 4=xg 5=hg  (96 VGPRs)
  short8 wf[6][4];
  {
    const float* Wm[6] = {xu_w, hu_w, xr_w, hr_w, xg_w, hg_w};
#pragma unroll
    for (int M = 0; M < 6; ++M)
#pragma unroll
      for (int ks = 0; ks < 4; ++ks) {
        const float* p = Wm[M] + o * H_ + ks * 32 + q * 8;
        short8 v;
#pragma unroll
        for (int j = 0; j < 8; ++j) v[j] = f2bf(p[j]);
        wf[M][ks] = v;
      }
  }
  // biases for this lane's 4 output cols (f32x4, 16B-aligned: ob % 4 == 0)
  const f32x4 bu4 = *(const f32x4*)(xu_b + ob) + *(const f32x4*)(hu_b + ob);
  const f32x4 br4 = *(const f32x4*)(xr_b + ob) + *(const f32x4*)(hr_b + ob);
  const f32x4 bxg4 = *(const f32x4*)(xg_b + ob);
  const f32x4 bhg4 = *(const f32x4*)(hg_b + ob);

  for (int i = tid; i < 16 * 128; i += 512) hbuf[0][i] = 0;

  // --- x-fragment prefetch state ---
  typedef union { uint4 u; short8 s; } frag_u;
  frag_u xp[2][4];  // xp[f&1] holds x-frags for step f (DIRECT path)
  const short* px = histbf + ((size_t)bb * T_ * 4) * 512 + (size_t)lane * 8;
  // --- fallback staging state ---
  const int sm = tid >> 5, cs = tid & 31;
  const int xpos = sm * 128 + (((cs >> 1) ^ (sm & 7)) * 8) + (cs & 1) * 4;
  const float* hrow = hist + ((size_t)(r0 + sm) * T_) * H_ + cs * 4;
  float4 xnext;

  // x-accumulators, double-state: xq[t&1] = {xu,xr,xg} partials for step t,
  // bias-seeded. xq[0] (t=0) computed in prologue; in-loop step t computes
  // xq[(t+1)&1] from prefetched frags, overlapping gate VALU.
  f32x4 xq[2][3];

  if constexpr (DIRECT) {
    frag_u x0[4];
#pragma unroll
    for (int ks = 0; ks < 4; ++ks)
      x0[ks].u = *(const uint4*)(px + (size_t)(0 * 4 + ks) * 512);
#pragma unroll
    for (int ks = 0; ks < 4; ++ks)
      xp[1][ks].u = *(const uint4*)(px + (size_t)(1 * 4 + ks) * 512);
#pragma unroll
    for (int ks = 0; ks < 4; ++ks)
      xp[0][ks].u = *(const uint4*)(px + (size_t)(2 * 4 + ks) * 512);
    // xacc(0), bias-seeded
    xq[0][0] = bu4;
    xq[0][1] = br4;
    xq[0][2] = bxg4;
#pragma unroll
    for (int ks = 0; ks < 4; ++ks) {
      xq[0][0] = MFMA(wf[0][ks], x0[ks].s, xq[0][0]);
      xq[0][1] = MFMA(wf[2][ks], x0[ks].s, xq[0][1]);
      xq[0][2] = MFMA(wf[4][ks], x0[ks].s, xq[0][2]);
    }
  } else {
    float4 a = *(const float4*)hrow;  // x(0)
    uint2 u;
    u.x = pack2bf_rne(a.x, a.y);
    u.y = pack2bf_rne(a.z, a.w);
    *(uint2*)&xbuf[0][xpos] = u;
    xnext = *(const float4*)(hrow + H_);  // x(1)
  }

  // att prefetch (depth 2): one value per lane (its batch row n), L1-resident
  float ap2[2];
  const float* pa = att + (size_t)(r0 + n) * T_;
  ap2[0] = pa[0];
  ap2[1] = pa[1];

  // this lane's h state: h[row n][cols ob..ob+3]
  float hreg[4] = {0.0f, 0.0f, 0.0f, 0.0f};
  // h write-back address: 4 consecutive cols inside one swizzle granule
  const int wri = n * 128 + (((w * 2 + (q >> 1)) ^ (n & 7)) * 8) + (q & 1) * 4;
  ck_barrier();

#pragma unroll 2
  for (int t = 0; t < T_; ++t) {
    const int cur = t & 1, nxt = cur ^ 1;
    // h-frags for step t (recurrence-critical)
    short8 ha[4];
#pragma unroll
    for (int ks = 0; ks < 4; ++ks)
      ha[ks] = *(short8*)&hbuf[cur][n * 128 + ((ks * 4 + q) ^ (n & 7)) * 8];

    f32x4 ahu = {0, 0, 0, 0}, ahr = {0, 0, 0, 0}, ahg = {0, 0, 0, 0};
#pragma unroll
    for (int ks = 0; ks < 4; ++ks) {
      ahu = MFMA(wf[1][ks], ha[ks], ahu);
      ahr = MFMA(wf[3][ks], ha[ks], ahr);
      ahg = MFMA(wf[5][ks], ha[ks], ahg);
    }

    if constexpr (DIRECT) {
      // ---- pipelined x-side: compute xacc(t+1) now; matrix pipe crunches
      // these while the gate VALU below runs (gates don't depend on them).
      xq[nxt][0] = bu4;
      xq[nxt][1] = br4;
      xq[nxt][2] = bxg4;
#pragma unroll
      for (int ks = 0; ks < 4; ++ks) {
        short8 xs = xp[nxt][ks].s;  // frags for step t+1 (slot (t+1)&1)
        xq[nxt][0] = MFMA(wf[0][ks], xs, xq[nxt][0]);
        xq[nxt][1] = MFMA(wf[2][ks], xs, xq[nxt][1]);
        xq[nxt][2] = MFMA(wf[4][ks], xs, xq[nxt][2]);
      }
      // reload slot (t+1)&1 with frags for step t+3 (2-step lead)
      const int tf = (t + 3 < T_) ? t + 3 : T_ - 1;
#pragma unroll
      for (int ks = 0; ks < 4; ++ks)
        xp[nxt][ks].u = *(const uint4*)(px + (size_t)(tf * 4 + ks) * 512);
    } else {
      // fallback: x-MFMAs in-step from LDS-staged x(t)
      short8 xa[4];
#pragma unroll
      for (int ks = 0; ks < 4; ++ks)
        xa[ks] = *(short8*)&xbuf[cur][n * 128 + ((ks * 4 + q) ^ (n & 7)) * 8];
      xq[cur][0] = bu4;
      xq[cur][1] = br4;
      xq[cur][2] = bxg4;
#pragma unroll
      for (int ks = 0; ks < 4; ++ks) {
        xq[cur][0] = MFMA(wf[0][ks], xa[ks], xq[cur][0]);
        xq[cur][1] = MFMA(wf[2][ks], xa[ks], xq[cur][1]);
        xq[cur][2] = MFMA(wf[4][ks], xa[ks], xq[cur][2]);
      }
      const int tp = (t + 2 < T_) ? t + 2 : T_ - 1;
      uint2 u;
      u.x = pack2bf_rne(xnext.x, xnext.y);
      u.y = pack2bf_rne(xnext.z, xnext.w);
      *(uint2*)&xbuf[nxt][xpos] = u;  // stage x(t+1)
      xnext = *(const float4*)(hrow + (size_t)tp * H_);
    }

    const int tp = (t + 2 < T_) ? t + 2 : T_ - 1;
    const float at = ap2[cur];
    ap2[cur] = pa[tp];

    // gates + h update (rcp-based, no IEEE division); biases pre-seeded in xq
    float hn[4];
#pragma unroll
    for (int r = 0; r < 4; ++r) {
      const float su = xq[cur][0][r] + ahu[r];
      const float u = at * rcp_f(1.0f + __expf(-su));
      const float sr = xq[cur][1][r] + ahr[r];
      const float rr = rcp_f(1.0f + __expf(-sr));
      const float sg = xq[cur][2][r] + rr * (ahg[r] + bhg4[r]);
      const float g = 2.0f * rcp_f(1.0f + __expf(-2.0f * sg)) - 1.0f;
      hn[r] = hreg[r] + u * (g - hreg[r]);
      hreg[r] = hn[r];
    }
    // single 8B LDS write: 4 consecutive bf16 cols of row n
    uint2 up;
    up.x = pack2bf_trunc(hn[0], hn[1]);
    up.y = pack2bf_trunc(hn[2], hn[3]);
    *(uint2*)&hbuf[nxt][wri] = up;
    ck_barrier();
  }

  // final h store (hreg holds h(T-1))
  f32x4 hv = {hreg[0], hreg[1], hreg[2], hreg[3]};
  *(f32x4*)(h_out + (size_t)(r0 + n) * H_ + ob) = hv;
}

// ---------------------------------------------------------------------------
// K_D: out = [h | targets[:,0]] @ ln2_w^T + ln2_b (fp32)
// ---------------------------------------------------------------------------
__global__ __launch_bounds__(256, 4) void final_kernel(
    const float* __restrict__ tgt, const float* __restrict__ hfin,
    const float* __restrict__ w, const float* __restrict__ bias,
    float* __restrict__ out) {
  const int b = blockIdx.x, tid = threadIdx.x;
  const int o = tid >> 1, half = tid & 1;
  const float* src = half ? (tgt + (size_t)b * (T_ * H_)) : (hfin + (size_t)b * H_);
  const float* wrow = w + o * 256 + half * 128;
  float acc = 0.0f;
#pragma unroll 8
  for (int k = 0; k < 128; k += 4) {
    float4 sv = *(const float4*)(src + k);
    float4 wv = *(const float4*)(wrow + k);
    acc += sv.x * wv.x + sv.y * wv.y + sv.z * wv.z + sv.w * wv.w;
  }
  acc += __shfl_xor(acc, 1);
  if (half == 0) out[(size_t)b * H_ + o] = acc + bias[o];
}

extern "C" void kernel_launch(void* const* d_in, const int* in_sizes, int n_in,
                              void* d_out, int out_size, void* d_ws, size_t ws_size,
                              hipStream_t stream) {
  const float* targets = (const float*)d_in[0];
  const float* history = (const float*)d_in[1];
  const float* W_w = (const float*)d_in[2];
  const float* W_b = (const float*)d_in[3];
  const float* xu_w = (const float*)d_in[4];
  const float* xu_b = (const float*)d_in[5];
  const float* hu_w = (const float*)d_in[6];
  const float* hu_b = (const float*)d_in[7];
  const float* xr_w = (const float*)d_in[8];
  const float* xr_b = (const float*)d_in[9];
  const float* hr_w = (const float*)d_in[10];
  const float* hr_b = (const float*)d_in[11];
  const float* xg_w = (const float*)d_in[12];
  const float* xg_b = (const float*)d_in[13];
  const float* hg_w = (const float*)d_in[14];
  const float* hg_b = (const float*)d_in[15];
  const float* ln2_w = (const float*)d_in[16];
  const float* ln2_b = (const float*)d_in[17];
  float* out = (float*)d_out;

  float* att = (float*)d_ws;            // [B,T] f32
  float* hfin = att + (size_t)B_ * T_;  // [B,H] f32
  const size_t fixed = (size_t)B_ * T_ * 4 + (size_t)B_ * H_ * 4;
  const size_t histbf_bytes = (size_t)64 * T_ * 4 * 512 * 8 * 2;  // 52.4 MB
  short* histbf = (ws_size >= fixed + histbf_bytes)
                      ? (short*)((char*)d_ws + fixed)
                      : nullptr;

  proj_scores_kernel<<<dim3(13, 64), dim3(512), 0, stream>>>(
      targets, history, W_w, W_b, att, histbf);
  softmax_kernel<<<dim3(B_), dim3(256), 0, stream>>>(att);
  if (histbf) {
    scan3_kernel<true><<<dim3(64), dim3(512), 0, stream>>>(
        history, xu_w, xu_b, hu_w, hu_b, xr_w, xr_b, hr_w, hr_b,
        xg_w, xg_b, hg_w, hg_b, att, histbf, hfin);
  } else {
    scan3_kernel<false><<<dim3(64), dim3(512), 0, stream>>>(
        history, xu_w, xu_b, hu_w, hu_b, xr_w, xr_b, hr_w, hr_b,
        xg_w, xg_b, hg_w, hg_b, att, histbf, hfin);
  }
  final_kernel<<<dim3(B_), dim3(256), 0, stream>>>(targets, hfin, ln2_w, ln2_b, out);
}

// Round 3
// 464.876 us; speedup vs baseline: 1.0656x; 1.0140x over previous
//
#include <hip/hip_runtime.h>

#define B_ 1024
#define T_ 200
#define H_ 128

typedef __attribute__((ext_vector_type(8))) short short8;
typedef __attribute__((ext_vector_type(4))) float f32x4;

#define MFMA(a, b, c) __builtin_amdgcn_mfma_f32_16x16x32_bf16((a), (b), (c), 0, 0, 0)

static __device__ __forceinline__ short f2bf(float f) {
  unsigned u = __float_as_uint(f);
  u += 0x7fffu + ((u >> 16) & 1u);  // RNE
  return (short)(u >> 16);
}
static __device__ __forceinline__ float bf2f(short s) {
  return __uint_as_float(((unsigned)(unsigned short)s) << 16);
}
// pack two floats as bf16 (RNE) into one dword: low short = a, high short = b
static __device__ __forceinline__ unsigned pack2bf_rne(float a, float b) {
  unsigned ua = __float_as_uint(a);
  ua += 0x7fffu + ((ua >> 16) & 1u);
  unsigned ub = __float_as_uint(b);
  ub += 0x7fffu + ((ub >> 16) & 1u);
  return (ua >> 16) | (ub & 0xFFFF0000u);
}
// truncating pack (matches previous h-state rounding)
static __device__ __forceinline__ unsigned pack2bf_trunc(float a, float b) {
  return (__float_as_uint(a) >> 16) | (__float_as_uint(b) & 0xFFFF0000u);
}
static __device__ __forceinline__ float rcp_f(float x) { return __builtin_amdgcn_rcpf(x); }
// CK-style barrier: LDS-only drain, does NOT drain vmcnt (keeps global prefetch alive)
static __device__ __forceinline__ void ck_barrier() {
  asm volatile("s_waitcnt lgkmcnt(0)\n\ts_barrier" ::: "memory");
}

// ---------------------------------------------------------------------------
// K_A: attention scores (split bf16 3-pass, fp32-grade) + hist->bf16 repack
// into scan-native B-fragment-direct global layout. (unchanged)
// ---------------------------------------------------------------------------
__global__ __launch_bounds__(512, 1) void proj_scores_kernel(
    const float* __restrict__ tgt, const float* __restrict__ hist,
    const float* __restrict__ Ww, const float* __restrict__ Wb,
    float* __restrict__ scores, short* __restrict__ histbf) {
  const int tc = blockIdx.x, bb = blockIdx.y;
  const int nt = (tc == 12) ? 8 : 16;
  const int t0 = tc * 16;
  const int tid = threadIdx.x;
  const int lane = tid & 63, w = tid >> 6;
  const int n = lane & 15, q = lane >> 4;

  __shared__ short tgt_hi[2][16 * 128];
  __shared__ short tgt_lo[2][16 * 128];
  __shared__ float hist_f[2][16 * 132];  // padded rows
  __shared__ float sp[16 * 8];

  // register A-frags for Ww (hi/lo split): A[i][k] = Ww[w*16+i][k]
  short8 whi[4], wlo[4];
  f32x4 wb4;
  {
    const int o = w * 16 + n;
#pragma unroll
    for (int ks = 0; ks < 4; ++ks) {
      const float* p = Ww + o * H_ + ks * 32 + q * 8;
      short8 h, l;
#pragma unroll
      for (int j = 0; j < 8; ++j) {
        float f = p[j];
        short hv = f2bf(f);
        h[j] = hv;
        l[j] = f2bf(f - bf2f(hv));
      }
      whi[ks] = h;
      wlo[ks] = l;
    }
    wb4 = *(const f32x4*)(Wb + w * 16 + q * 4);  // biases for this lane's 4 cols
  }

  // staging: thread -> (row sm, 4-float granule cs)
  const int sm = tid >> 5, cs = tid & 31;
  const int g = cs >> 1, half = cs & 1;
  const int spos16 = sm * 128 + ((g ^ (sm & 7)) * 8) + half * 4;  // shorts
  const int sposf = sm * 132 + cs * 4;                            // floats
  const size_t rowbase = ((size_t)(bb * 16 + sm) * T_) * H_ + cs * 4;

  // histbf conversion mapping: thread handles 8 bytes (4 shorts)
  const int cu = tid;
  const int cks = cu >> 7, crem = cu & 127, cwl = crem >> 1, chalf = crem & 1;
  const int crow = cwl & 15, ckb = cks * 32 + (cwl >> 4) * 8 + chalf * 4;

  float4 hv = *(const float4*)(hist + rowbase + (size_t)t0 * H_);
  float4 tv = *(const float4*)(tgt + rowbase + (size_t)t0 * H_);
  {
    *(float4*)&hist_f[0][sposf] = hv;
    uint2 hi, lo;
    hi.x = pack2bf_rne(tv.x, tv.y);
    hi.y = pack2bf_rne(tv.z, tv.w);
    lo.x = pack2bf_rne(tv.x - bf2f((short)(hi.x)), tv.y - bf2f((short)(hi.x >> 16)));
    lo.y = pack2bf_rne(tv.z - bf2f((short)(hi.y)), tv.w - bf2f((short)(hi.y >> 16)));
    *(uint2*)&tgt_hi[0][spos16] = hi;
    *(uint2*)&tgt_lo[0][spos16] = lo;
  }
  ck_barrier();

  for (int tl = 0; tl < nt; ++tl) {
    const int cur = tl & 1, nxt = cur ^ 1;
    const bool have_next = (tl + 1 < nt);
    if (have_next) {
      hv = *(const float4*)(hist + rowbase + (size_t)(t0 + tl + 1) * H_);
      tv = *(const float4*)(tgt + rowbase + (size_t)(t0 + tl + 1) * H_);
    }
    // scores MFMA: 3-pass split bf16, swapped operands (A = W, B = tgt)
    f32x4 s1 = {0, 0, 0, 0}, s2 = {0, 0, 0, 0}, s3 = {0, 0, 0, 0};
#pragma unroll
    for (int ks = 0; ks < 4; ++ks) {
      const int fp = n * 128 + ((ks * 4 + q) ^ (n & 7)) * 8;
      short8 ahi = *(short8*)&tgt_hi[cur][fp];
      short8 alo = *(short8*)&tgt_lo[cur][fp];
      s1 = MFMA(whi[ks], ahi, s1);
      s2 = MFMA(wlo[ks], ahi, s2);
      s3 = MFMA(whi[ks], alo, s3);
    }
    // dot with hist (fp32): lane holds (row n, cols w*16+q*4..+3)
    {
      f32x4 hv4 = *(const f32x4*)&hist_f[cur][n * 132 + w * 16 + q * 4];
      float v = (s1[0] + s2[0] + s3[0] + wb4[0]) * hv4[0];
      v += (s1[1] + s2[1] + s3[1] + wb4[1]) * hv4[1];
      v += (s1[2] + s2[2] + s3[2] + wb4[2]) * hv4[2];
      v += (s1[3] + s2[3] + s3[3] + wb4[3]) * hv4[3];
      v += __shfl_xor(v, 16);
      v += __shfl_xor(v, 32);
      if (lane < 16) sp[n * 8 + w] = v;
    }
    // hist -> bf16 packed global (scan-native layout), once per element
    if (histbf != nullptr) {
      const float* src = &hist_f[cur][crow * 132 + ckb];
      uint2 u;
      u.x = pack2bf_rne(src[0], src[1]);
      u.y = pack2bf_rne(src[2], src[3]);
      const size_t sb = (((size_t)(bb * T_ + t0 + tl) * 4) + cks) * 512 + cwl * 8 + chalf * 4;
      *(uint2*)(histbf + sb) = u;
    }
    // stage next tile (prefetched regs)
    if (have_next) {
      *(float4*)&hist_f[nxt][sposf] = hv;
      uint2 hi, lo;
      hi.x = pack2bf_rne(tv.x, tv.y);
      hi.y = pack2bf_rne(tv.z, tv.w);
      lo.x = pack2bf_rne(tv.x - bf2f((short)(hi.x)), tv.y - bf2f((short)(hi.x >> 16)));
      lo.y = pack2bf_rne(tv.z - bf2f((short)(hi.y)), tv.w - bf2f((short)(hi.y >> 16)));
      *(uint2*)&tgt_hi[nxt][spos16] = hi;
      *(uint2*)&tgt_lo[nxt][spos16] = lo;
    }
    ck_barrier();
    if (tid < 16) {
      float s = 0.0f;
#pragma unroll
      for (int ww = 0; ww < 8; ++ww) s += sp[tid * 8 + ww];
      scores[(size_t)(bb * 16 + tid) * T_ + (t0 + tl)] = s;
    }
    ck_barrier();
  }
}

// ---------------------------------------------------------------------------
// K_B: softmax over T, in place. One block per batch row.
// ---------------------------------------------------------------------------
__global__ __launch_bounds__(256, 4) void softmax_kernel(float* __restrict__ att) {
  const int b = blockIdx.x, tid = threadIdx.x;
  const int lane = tid & 63, wave = tid >> 6;
  __shared__ float red[8];
  float v = (tid < T_) ? att[(size_t)b * T_ + tid] : -3.0e38f;
  float mx = v;
#pragma unroll
  for (int d = 1; d < 64; d <<= 1) mx = fmaxf(mx, __shfl_xor(mx, d));
  if (lane == 0) red[wave] = mx;
  __syncthreads();
  mx = fmaxf(fmaxf(red[0], red[1]), fmaxf(red[2], red[3]));
  float e = (tid < T_) ? __expf(v - mx) : 0.0f;
  float sm = e;
#pragma unroll
  for (int d = 1; d < 64; d <<= 1) sm += __shfl_xor(sm, d);
  if (lane == 0) red[4 + wave] = sm;
  __syncthreads();
  sm = red[4] + red[5] + red[6] + red[7];
  if (tid < T_) att[(size_t)b * T_ + tid] = e / sm;
}

// ---------------------------------------------------------------------------
// K_C: recurrent scan v6. 64 blocks x 16 rows, 512 threads (8 waves).
// ISSUE-INTERLEAVED x-side: R2's measured counters showed zero MFMA||VALU
// overlap (MFMA busy 753 + VALU busy 1170 + sync 230 ~= step 2214 cyc/SIMD):
// in-order issue head-of-line blocking — the 12-deep x-MFMA cluster
// backpressured the matrix pipe and the independent gate VALU sat behind it.
// Fix: issue exactly 3 x-MFMAs per gate iteration r (~58 pipe-cyc/SIMD of
// MFMA vs ~68 issue-cyc of gate VALU+trans — balanced), so the matrix pipe
// drains the x-side of step t+1 WHILE the VALU computes gates of step t.
// ahg chain C-seeded with bhg (kills 4 VALU adds/step). ds_write of h
// immediately after last gate so barrier drain starts ASAP.
// ---------------------------------------------------------------------------
template <bool DIRECT>
__global__ __launch_bounds__(512, 1) void scan3_kernel(
    const float* __restrict__ hist,
    const float* __restrict__ xu_w, const float* __restrict__ xu_b,
    const float* __restrict__ hu_w, const float* __restrict__ hu_b,
    const float* __restrict__ xr_w, const float* __restrict__ xr_b,
    const float* __restrict__ hr_w, const float* __restrict__ hr_b,
    const float* __restrict__ xg_w, const float* __restrict__ xg_b,
    const float* __restrict__ hg_w, const float* __restrict__ hg_b,
    const float* __restrict__ att, const short* __restrict__ histbf,
    float* __restrict__ h_out) {
  const int tid = threadIdx.x;
  const int lane = tid & 63, w = tid >> 6;
  const int n = lane & 15, q = lane >> 4;
  const int bb = blockIdx.x, r0 = bb * 16;
  const int o = w * 16 + n;       // A-frag packing index (W rows = output cols)
  const int ob = w * 16 + q * 4;  // this lane's 4 output cols (D layout)

  __shared__ short hbuf[2][16 * 128];
  __shared__ short xbuf[2][16 * 128];  // only used when !DIRECT

  // A-frags: 0=xu 1=hu 2=xr 3=hr 4=xg 5=hg  (96 VGPRs)
  short8 wf[6][4];
  {
    const float* Wm[6] = {xu_w, hu_w, xr_w, hr_w, xg_w, hg_w};
#pragma unroll
    for (int M = 0; M < 6; ++M)
#pragma unroll
      for (int ks = 0; ks < 4; ++ks) {
        const float* p = Wm[M] + o * H_ + ks * 32 + q * 8;
        short8 v;
#pragma unroll
        for (int j = 0; j < 8; ++j) v[j] = f2bf(p[j]);
        wf[M][ks] = v;
      }
  }
  // biases for this lane's 4 output cols (f32x4, 16B-aligned: ob % 4 == 0)
  const f32x4 bu4 = *(const f32x4*)(xu_b + ob) + *(const f32x4*)(hu_b + ob);
  const f32x4 br4 = *(const f32x4*)(xr_b + ob) + *(const f32x4*)(hr_b + ob);
  const f32x4 bxg4 = *(const f32x4*)(xg_b + ob);
  const f32x4 bhg4 = *(const f32x4*)(hg_b + ob);

  for (int i = tid; i < 16 * 128; i += 512) hbuf[0][i] = 0;

  // --- x-fragment prefetch state ---
  typedef union { uint4 u; short8 s; } frag_u;
  frag_u xp[2][4];  // xp[f&1] holds x-frags for step f (DIRECT path)
  const short* px = histbf + ((size_t)bb * T_ * 4) * 512 + (size_t)lane * 8;
  // --- fallback staging state ---
  const int sm = tid >> 5, cs = tid & 31;
  const int xpos = sm * 128 + (((cs >> 1) ^ (sm & 7)) * 8) + (cs & 1) * 4;
  const float* hrow = hist + ((size_t)(r0 + sm) * T_) * H_ + cs * 4;
  float4 xnext;

  // x-accumulators, double-state: xq[t&1] = {xu,xr,xg} partials for step t,
  // bias-seeded. xq[0] (t=0) computed in prologue; in-loop step t computes
  // xq[(t+1)&1] interleaved with the gate VALU.
  f32x4 xq[2][3];

  if constexpr (DIRECT) {
    frag_u x0[4];
#pragma unroll
    for (int ks = 0; ks < 4; ++ks)
      x0[ks].u = *(const uint4*)(px + (size_t)(0 * 4 + ks) * 512);
#pragma unroll
    for (int ks = 0; ks < 4; ++ks)
      xp[1][ks].u = *(const uint4*)(px + (size_t)(1 * 4 + ks) * 512);
#pragma unroll
    for (int ks = 0; ks < 4; ++ks)
      xp[0][ks].u = *(const uint4*)(px + (size_t)(2 * 4 + ks) * 512);
    // xacc(0), bias-seeded
    xq[0][0] = bu4;
    xq[0][1] = br4;
    xq[0][2] = bxg4;
#pragma unroll
    for (int ks = 0; ks < 4; ++ks) {
      xq[0][0] = MFMA(wf[0][ks], x0[ks].s, xq[0][0]);
      xq[0][1] = MFMA(wf[2][ks], x0[ks].s, xq[0][1]);
      xq[0][2] = MFMA(wf[4][ks], x0[ks].s, xq[0][2]);
    }
  } else {
    float4 a = *(const float4*)hrow;  // x(0)
    uint2 u;
    u.x = pack2bf_rne(a.x, a.y);
    u.y = pack2bf_rne(a.z, a.w);
    *(uint2*)&xbuf[0][xpos] = u;
    xnext = *(const float4*)(hrow + H_);  // x(1)
  }

  // att prefetch (depth 2): one value per lane (its batch row n), L1-resident
  float ap2[2];
  const float* pa = att + (size_t)(r0 + n) * T_;
  ap2[0] = pa[0];
  ap2[1] = pa[1];

  // this lane's h state: h[row n][cols ob..ob+3]
  float hreg[4] = {0.0f, 0.0f, 0.0f, 0.0f};
  // h write-back address: 4 consecutive cols inside one swizzle granule
  const int wri = n * 128 + (((w * 2 + (q >> 1)) ^ (n & 7)) * 8) + (q & 1) * 4;
  ck_barrier();

#pragma unroll 2
  for (int t = 0; t < T_; ++t) {
    const int cur = t & 1, nxt = cur ^ 1;
    // h-frags for step t (recurrence-critical) — issue reads first
    short8 ha[4];
#pragma unroll
    for (int ks = 0; ks < 4; ++ks)
      ha[ks] = *(short8*)&hbuf[cur][n * 128 + ((ks * 4 + q) ^ (n & 7)) * 8];

    // h-side MFMA chains; ahg C-seeded with bhg
    f32x4 ahu = {0, 0, 0, 0}, ahr = {0, 0, 0, 0}, ahg = bhg4;
#pragma unroll
    for (int ks = 0; ks < 4; ++ks) {
      ahu = MFMA(wf[1][ks], ha[ks], ahu);
      ahr = MFMA(wf[3][ks], ha[ks], ahr);
      ahg = MFMA(wf[5][ks], ha[ks], ahg);
    }

    if constexpr (!DIRECT) {
      // fallback: x-MFMAs in-step from LDS-staged x(t)
      short8 xa[4];
#pragma unroll
      for (int ks = 0; ks < 4; ++ks)
        xa[ks] = *(short8*)&xbuf[cur][n * 128 + ((ks * 4 + q) ^ (n & 7)) * 8];
      xq[cur][0] = bu4;
      xq[cur][1] = br4;
      xq[cur][2] = bxg4;
#pragma unroll
      for (int ks = 0; ks < 4; ++ks) {
        xq[cur][0] = MFMA(wf[0][ks], xa[ks], xq[cur][0]);
        xq[cur][1] = MFMA(wf[2][ks], xa[ks], xq[cur][1]);
        xq[cur][2] = MFMA(wf[4][ks], xa[ks], xq[cur][2]);
      }
    }

    const int tp = (t + 2 < T_) ? t + 2 : T_ - 1;
    const float at = ap2[cur];
    ap2[cur] = pa[tp];

    // gates (step t) INTERLEAVED with x-side MFMA chunks (step t+1):
    // per r: ~10 VALU + 6 trans of gate work, then 3 x-MFMAs — the matrix
    // pipe crunches x(t+1) while the VALU does gates(t).
    float hn[4];
#pragma unroll
    for (int r = 0; r < 4; ++r) {
      const float su = xq[cur][0][r] + ahu[r];
      const float uu = at * rcp_f(1.0f + __expf(-su));
      const float sr = xq[cur][1][r] + ahr[r];
      const float rr = rcp_f(1.0f + __expf(-sr));
      const float sg = xq[cur][2][r] + rr * ahg[r];  // ahg already has +bhg
      const float g = 2.0f * rcp_f(1.0f + __expf(-2.0f * sg)) - 1.0f;
      hn[r] = hreg[r] + uu * (g - hreg[r]);
      hreg[r] = hn[r];
      if constexpr (DIRECT) {
        const short8 xs = xp[nxt][r].s;  // frag chunk ks=r for step t+1
        xq[nxt][0] = MFMA(wf[0][r], xs, (r == 0) ? bu4 : xq[nxt][0]);
        xq[nxt][1] = MFMA(wf[2][r], xs, (r == 0) ? br4 : xq[nxt][1]);
        xq[nxt][2] = MFMA(wf[4][r], xs, (r == 0) ? bxg4 : xq[nxt][2]);
      }
    }

    // single 8B LDS write ASAP: 4 consecutive bf16 cols of row n
    uint2 up;
    up.x = pack2bf_trunc(hn[0], hn[1]);
    up.y = pack2bf_trunc(hn[2], hn[3]);
    *(uint2*)&hbuf[nxt][wri] = up;

    if constexpr (DIRECT) {
      // reload slot (t+1)&1 with frags for step t+3 (2-step lead)
      const int tf = (t + 3 < T_) ? t + 3 : T_ - 1;
#pragma unroll
      for (int ks = 0; ks < 4; ++ks)
        xp[nxt][ks].u = *(const uint4*)(px + (size_t)(tf * 4 + ks) * 512);
    } else {
      uint2 u;
      u.x = pack2bf_rne(xnext.x, xnext.y);
      u.y = pack2bf_rne(xnext.z, xnext.w);
      *(uint2*)&xbuf[nxt][xpos] = u;  // stage x(t+1)
      xnext = *(const float4*)(hrow + (size_t)tp * H_);
    }
    ck_barrier();
  }

  // final h store (hreg holds h(T-1))
  f32x4 hv = {hreg[0], hreg[1], hreg[2], hreg[3]};
  *(f32x4*)(h_out + (size_t)(r0 + n) * H_ + ob) = hv;
}

// ---------------------------------------------------------------------------
// K_D: out = [h | targets[:,0]] @ ln2_w^T + ln2_b (fp32)
// ---------------------------------------------------------------------------
__global__ __launch_bounds__(256, 4) void final_kernel(
    const float* __restrict__ tgt, const float* __restrict__ hfin,
    const float* __restrict__ w, const float* __restrict__ bias,
    float* __restrict__ out) {
  const int b = blockIdx.x, tid = threadIdx.x;
  const int o = tid >> 1, half = tid & 1;
  const float* src = half ? (tgt + (size_t)b * (T_ * H_)) : (hfin + (size_t)b * H_);
  const float* wrow = w + o * 256 + half * 128;
  float acc = 0.0f;
#pragma unroll 8
  for (int k = 0; k < 128; k += 4) {
    float4 sv = *(const float4*)(src + k);
    float4 wv = *(const float4*)(wrow + k);
    acc += sv.x * wv.x + sv.y * wv.y + sv.z * wv.z + sv.w * wv.w;
  }
  acc += __shfl_xor(acc, 1);
  if (half == 0) out[(size_t)b * H_ + o] = acc + bias[o];
}

extern "C" void kernel_launch(void* const* d_in, const int* in_sizes, int n_in,
                              void* d_out, int out_size, void* d_ws, size_t ws_size,
                              hipStream_t stream) {
  const float* targets = (const float*)d_in[0];
  const float* history = (const float*)d_in[1];
  const float* W_w = (const float*)d_in[2];
  const float* W_b = (const float*)d_in[3];
  const float* xu_w = (const float*)d_in[4];
  const float* xu_b = (const float*)d_in[5];
  const float* hu_w = (const float*)d_in[6];
  const float* hu_b = (const float*)d_in[7];
  const float* xr_w = (const float*)d_in[8];
  const float* xr_b = (const float*)d_in[9];
  const float* hr_w = (const float*)d_in[10];
  const float* hr_b = (const float*)d_in[11];
  const float* xg_w = (const float*)d_in[12];
  const float* xg_b = (const float*)d_in[13];
  const float* hg_w = (const float*)d_in[14];
  const float* hg_b = (const float*)d_in[15];
  const float* ln2_w = (const float*)d_in[16];
  const float* ln2_b = (const float*)d_in[17];
  float* out = (float*)d_out;

  float* att = (float*)d_ws;            // [B,T] f32
  float* hfin = att + (size_t)B_ * T_;  // [B,H] f32
  const size_t fixed = (size_t)B_ * T_ * 4 + (size_t)B_ * H_ * 4;
  const size_t histbf_bytes = (size_t)64 * T_ * 4 * 512 * 8 * 2;  // 52.4 MB
  short* histbf = (ws_size >= fixed + histbf_bytes)
                      ? (short*)((char*)d_ws + fixed)
                      : nullptr;

  proj_scores_kernel<<<dim3(13, 64), dim3(512), 0, stream>>>(
      targets, history, W_w, W_b, att, histbf);
  softmax_kernel<<<dim3(B_), dim3(256), 0, stream>>>(att);
  if (histbf) {
    scan3_kernel<true><<<dim3(64), dim3(512), 0, stream>>>(
        history, xu_w, xu_b, hu_w, hu_b, xr_w, xr_b, hr_w, hr_b,
        xg_w, xg_b, hg_w, hg_b, att, histbf, hfin);
  } else {
    scan3_kernel<false><<<dim3(64), dim3(512), 0, stream>>>(
        history, xu_w, xu_b, hu_w, hu_b, xr_w, xr_b, hr_w, hr_b,
        xg_w, xg_b, hg_w, hg_b, att, histbf, hfin);
  }
  final_kernel<<<dim3(B_), dim3(256), 0, stream>>>(targets, hfin, ln2_w, ln2_b, out);
}

// Round 4
// 450.082 us; speedup vs baseline: 1.1007x; 1.0329x over previous
//
#include <hip/hip_runtime.h>

#define B_ 1024
#define T_ 200
#define H_ 128

typedef __attribute__((ext_vector_type(8))) short short8;
typedef __attribute__((ext_vector_type(4))) float f32x4;

#define MFMA(a, b, c) __builtin_amdgcn_mfma_f32_16x16x32_bf16((a), (b), (c), 0, 0, 0)

// sched_group_barrier masks (LLVM SchedGroupMask)
#define SGB(mask, n) __builtin_amdgcn_sched_group_barrier((mask), (n), 0)
#define SG_VALU 0x2
#define SG_MFMA 0x8
#define SG_VMEM_RD 0x20
#define SG_DS_RD 0x100
#define SG_DS_WR 0x200

static __device__ __forceinline__ short f2bf(float f) {
  unsigned u = __float_as_uint(f);
  u += 0x7fffu + ((u >> 16) & 1u);  // RNE
  return (short)(u >> 16);
}
static __device__ __forceinline__ float bf2f(short s) {
  return __uint_as_float(((unsigned)(unsigned short)s) << 16);
}
// pack two floats as bf16 (RNE) into one dword: low short = a, high short = b
static __device__ __forceinline__ unsigned pack2bf_rne(float a, float b) {
  unsigned ua = __float_as_uint(a);
  ua += 0x7fffu + ((ua >> 16) & 1u);
  unsigned ub = __float_as_uint(b);
  ub += 0x7fffu + ((ub >> 16) & 1u);
  return (ua >> 16) | (ub & 0xFFFF0000u);
}
// truncating pack (matches previous h-state rounding)
static __device__ __forceinline__ unsigned pack2bf_trunc(float a, float b) {
  return (__float_as_uint(a) >> 16) | (__float_as_uint(b) & 0xFFFF0000u);
}
static __device__ __forceinline__ float rcp_f(float x) { return __builtin_amdgcn_rcpf(x); }
static __device__ __forceinline__ float exp2_f(float x) { return __builtin_amdgcn_exp2f(x); }
// CK-style barrier: LDS-only drain, does NOT drain vmcnt (keeps global prefetch alive)
static __device__ __forceinline__ void ck_barrier() {
  asm volatile("s_waitcnt lgkmcnt(0)\n\ts_barrier" ::: "memory");
}

// ---------------------------------------------------------------------------
// K_A: attention scores (split bf16 3-pass, fp32-grade) + hist->bf16 repack
// into scan-native B-fragment-direct global layout. (unchanged)
// ---------------------------------------------------------------------------
__global__ __launch_bounds__(512, 1) void proj_scores_kernel(
    const float* __restrict__ tgt, const float* __restrict__ hist,
    const float* __restrict__ Ww, const float* __restrict__ Wb,
    float* __restrict__ scores, short* __restrict__ histbf) {
  const int tc = blockIdx.x, bb = blockIdx.y;
  const int nt = (tc == 12) ? 8 : 16;
  const int t0 = tc * 16;
  const int tid = threadIdx.x;
  const int lane = tid & 63, w = tid >> 6;
  const int n = lane & 15, q = lane >> 4;

  __shared__ short tgt_hi[2][16 * 128];
  __shared__ short tgt_lo[2][16 * 128];
  __shared__ float hist_f[2][16 * 132];  // padded rows
  __shared__ float sp[16 * 8];

  // register A-frags for Ww (hi/lo split): A[i][k] = Ww[w*16+i][k]
  short8 whi[4], wlo[4];
  f32x4 wb4;
  {
    const int o = w * 16 + n;
#pragma unroll
    for (int ks = 0; ks < 4; ++ks) {
      const float* p = Ww + o * H_ + ks * 32 + q * 8;
      short8 h, l;
#pragma unroll
      for (int j = 0; j < 8; ++j) {
        float f = p[j];
        short hv = f2bf(f);
        h[j] = hv;
        l[j] = f2bf(f - bf2f(hv));
      }
      whi[ks] = h;
      wlo[ks] = l;
    }
    wb4 = *(const f32x4*)(Wb + w * 16 + q * 4);  // biases for this lane's 4 cols
  }

  // staging: thread -> (row sm, 4-float granule cs)
  const int sm = tid >> 5, cs = tid & 31;
  const int g = cs >> 1, half = cs & 1;
  const int spos16 = sm * 128 + ((g ^ (sm & 7)) * 8) + half * 4;  // shorts
  const int sposf = sm * 132 + cs * 4;                            // floats
  const size_t rowbase = ((size_t)(bb * 16 + sm) * T_) * H_ + cs * 4;

  // histbf conversion mapping: thread handles 8 bytes (4 shorts)
  const int cu = tid;
  const int cks = cu >> 7, crem = cu & 127, cwl = crem >> 1, chalf = crem & 1;
  const int crow = cwl & 15, ckb = cks * 32 + (cwl >> 4) * 8 + chalf * 4;

  float4 hv = *(const float4*)(hist + rowbase + (size_t)t0 * H_);
  float4 tv = *(const float4*)(tgt + rowbase + (size_t)t0 * H_);
  {
    *(float4*)&hist_f[0][sposf] = hv;
    uint2 hi, lo;
    hi.x = pack2bf_rne(tv.x, tv.y);
    hi.y = pack2bf_rne(tv.z, tv.w);
    lo.x = pack2bf_rne(tv.x - bf2f((short)(hi.x)), tv.y - bf2f((short)(hi.x >> 16)));
    lo.y = pack2bf_rne(tv.z - bf2f((short)(hi.y)), tv.w - bf2f((short)(hi.y >> 16)));
    *(uint2*)&tgt_hi[0][spos16] = hi;
    *(uint2*)&tgt_lo[0][spos16] = lo;
  }
  ck_barrier();

  for (int tl = 0; tl < nt; ++tl) {
    const int cur = tl & 1, nxt = cur ^ 1;
    const bool have_next = (tl + 1 < nt);
    if (have_next) {
      hv = *(const float4*)(hist + rowbase + (size_t)(t0 + tl + 1) * H_);
      tv = *(const float4*)(tgt + rowbase + (size_t)(t0 + tl + 1) * H_);
    }
    // scores MFMA: 3-pass split bf16, swapped operands (A = W, B = tgt)
    f32x4 s1 = {0, 0, 0, 0}, s2 = {0, 0, 0, 0}, s3 = {0, 0, 0, 0};
#pragma unroll
    for (int ks = 0; ks < 4; ++ks) {
      const int fp = n * 128 + ((ks * 4 + q) ^ (n & 7)) * 8;
      short8 ahi = *(short8*)&tgt_hi[cur][fp];
      short8 alo = *(short8*)&tgt_lo[cur][fp];
      s1 = MFMA(whi[ks], ahi, s1);
      s2 = MFMA(wlo[ks], ahi, s2);
      s3 = MFMA(whi[ks], alo, s3);
    }
    // dot with hist (fp32): lane holds (row n, cols w*16+q*4..+3)
    {
      f32x4 hv4 = *(const f32x4*)&hist_f[cur][n * 132 + w * 16 + q * 4];
      float v = (s1[0] + s2[0] + s3[0] + wb4[0]) * hv4[0];
      v += (s1[1] + s2[1] + s3[1] + wb4[1]) * hv4[1];
      v += (s1[2] + s2[2] + s3[2] + wb4[2]) * hv4[2];
      v += (s1[3] + s2[3] + s3[3] + wb4[3]) * hv4[3];
      v += __shfl_xor(v, 16);
      v += __shfl_xor(v, 32);
      if (lane < 16) sp[n * 8 + w] = v;
    }
    // hist -> bf16 packed global (scan-native layout), once per element
    if (histbf != nullptr) {
      const float* src = &hist_f[cur][crow * 132 + ckb];
      uint2 u;
      u.x = pack2bf_rne(src[0], src[1]);
      u.y = pack2bf_rne(src[2], src[3]);
      const size_t sb = (((size_t)(bb * T_ + t0 + tl) * 4) + cks) * 512 + cwl * 8 + chalf * 4;
      *(uint2*)(histbf + sb) = u;
    }
    // stage next tile (prefetched regs)
    if (have_next) {
      *(float4*)&hist_f[nxt][sposf] = hv;
      uint2 hi, lo;
      hi.x = pack2bf_rne(tv.x, tv.y);
      hi.y = pack2bf_rne(tv.z, tv.w);
      lo.x = pack2bf_rne(tv.x - bf2f((short)(hi.x)), tv.y - bf2f((short)(hi.x >> 16)));
      lo.y = pack2bf_rne(tv.z - bf2f((short)(hi.y)), tv.w - bf2f((short)(hi.y >> 16)));
      *(uint2*)&tgt_hi[nxt][spos16] = hi;
      *(uint2*)&tgt_lo[nxt][spos16] = lo;
    }
    ck_barrier();
    if (tid < 16) {
      float s = 0.0f;
#pragma unroll
      for (int ww = 0; ww < 8; ++ww) s += sp[tid * 8 + ww];
      scores[(size_t)(bb * 16 + tid) * T_ + (t0 + tl)] = s;
    }
    ck_barrier();
  }
}

// ---------------------------------------------------------------------------
// K_B: softmax over T, in place. One block per batch row.
// ---------------------------------------------------------------------------
__global__ __launch_bounds__(256, 4) void softmax_kernel(float* __restrict__ att) {
  const int b = blockIdx.x, tid = threadIdx.x;
  const int lane = tid & 63, wave = tid >> 6;
  __shared__ float red[8];
  float v = (tid < T_) ? att[(size_t)b * T_ + tid] : -3.0e38f;
  float mx = v;
#pragma unroll
  for (int d = 1; d < 64; d <<= 1) mx = fmaxf(mx, __shfl_xor(mx, d));
  if (lane == 0) red[wave] = mx;
  __syncthreads();
  mx = fmaxf(fmaxf(red[0], red[1]), fmaxf(red[2], red[3]));
  float e = (tid < T_) ? __expf(v - mx) : 0.0f;
  float sm = e;
#pragma unroll
  for (int d = 1; d < 64; d <<= 1) sm += __shfl_xor(sm, d);
  if (lane == 0) red[4 + wave] = sm;
  __syncthreads();
  sm = red[4] + red[5] + red[6] + red[7];
  if (tid < T_) att[(size_t)b * T_ + tid] = e / sm;
}

// ---------------------------------------------------------------------------
// K_C: recurrent scan v7. 64 blocks x 16 rows, 512 threads (8 waves).
// R3 counters proved pipes fully serialized (MFMA 745 + VALU 1135 + sync ~
// step 2118) despite source interleave -> compiler re-clusters MFMAs.
// v7: (a) T19 sched_group_barrier pins the emitted interleave:
//     [DS_READ 4][MFMA 12 h][VMEM_RD 5] then 4x{[VALU 16 gate][MFMA 3 x]}
//     then [VALU pack][DS_WRITE 1] -- x-MFMAs drain under gate VALU.
//     (b) exp2 prescale: log2e (u,r) / 2*log2e (g) folded into bf16 W-frag
//     and bias packing; gates call v_exp_f32 directly with free neg-modifier
//     (kills 3 v_mul + one 2.0f-mul per gate group).
// ---------------------------------------------------------------------------
template <bool DIRECT>
__global__ __launch_bounds__(512, 1) void scan3_kernel(
    const float* __restrict__ hist,
    const float* __restrict__ xu_w, const float* __restrict__ xu_b,
    const float* __restrict__ hu_w, const float* __restrict__ hu_b,
    const float* __restrict__ xr_w, const float* __restrict__ xr_b,
    const float* __restrict__ hr_w, const float* __restrict__ hr_b,
    const float* __restrict__ xg_w, const float* __restrict__ xg_b,
    const float* __restrict__ hg_w, const float* __restrict__ hg_b,
    const float* __restrict__ att, const short* __restrict__ histbf,
    float* __restrict__ h_out) {
  const int tid = threadIdx.x;
  const int lane = tid & 63, w = tid >> 6;
  const int n = lane & 15, q = lane >> 4;
  const int bb = blockIdx.x, r0 = bb * 16;
  const int o = w * 16 + n;       // A-frag packing index (W rows = output cols)
  const int ob = w * 16 + q * 4;  // this lane's 4 output cols (D layout)

  constexpr float LOG2E = 1.4426950408889634f;

  __shared__ short hbuf[2][16 * 128];
  __shared__ short xbuf[2][16 * 128];  // only used when !DIRECT

  // A-frags: 0=xu 1=hu 2=xr 3=hr 4=xg 5=hg  (96 VGPRs)
  // exp2-prescaled: u/r rows by log2e, g rows by 2*log2e.
  short8 wf[6][4];
  {
    const float* Wm[6] = {xu_w, hu_w, xr_w, hr_w, xg_w, hg_w};
    const float Sc[6] = {LOG2E, LOG2E, LOG2E, LOG2E, 2.0f * LOG2E, 2.0f * LOG2E};
#pragma unroll
    for (int M = 0; M < 6; ++M)
#pragma unroll
      for (int ks = 0; ks < 4; ++ks) {
        const float* p = Wm[M] + o * H_ + ks * 32 + q * 8;
        short8 v;
#pragma unroll
        for (int j = 0; j < 8; ++j) v[j] = f2bf(p[j] * Sc[M]);
        wf[M][ks] = v;
      }
  }
  // biases for this lane's 4 output cols, same prescale
  const f32x4 bu4 = (*(const f32x4*)(xu_b + ob) + *(const f32x4*)(hu_b + ob)) * LOG2E;
  const f32x4 br4 = (*(const f32x4*)(xr_b + ob) + *(const f32x4*)(hr_b + ob)) * LOG2E;
  const f32x4 bxg4 = *(const f32x4*)(xg_b + ob) * (2.0f * LOG2E);
  const f32x4 bhg4 = *(const f32x4*)(hg_b + ob) * (2.0f * LOG2E);

  for (int i = tid; i < 16 * 128; i += 512) hbuf[0][i] = 0;

  // --- x-fragment prefetch state ---
  typedef union { uint4 u; short8 s; } frag_u;
  frag_u xp[2][4];  // xp[f&1] holds x-frags for step f (DIRECT path)
  const short* px = histbf + ((size_t)bb * T_ * 4) * 512 + (size_t)lane * 8;
  // --- fallback staging state ---
  const int sm = tid >> 5, cs = tid & 31;
  const int xpos = sm * 128 + (((cs >> 1) ^ (sm & 7)) * 8) + (cs & 1) * 4;
  const float* hrow = hist + ((size_t)(r0 + sm) * T_) * H_ + cs * 4;
  float4 xnext;

  // x-accumulators, double-state: xq[t&1] = {xu,xr,xg} partials for step t,
  // bias-seeded (prescaled).
  f32x4 xq[2][3];

  if constexpr (DIRECT) {
    frag_u x0[4];
#pragma unroll
    for (int ks = 0; ks < 4; ++ks)
      x0[ks].u = *(const uint4*)(px + (size_t)(0 * 4 + ks) * 512);
#pragma unroll
    for (int ks = 0; ks < 4; ++ks)
      xp[1][ks].u = *(const uint4*)(px + (size_t)(1 * 4 + ks) * 512);
#pragma unroll
    for (int ks = 0; ks < 4; ++ks)
      xp[0][ks].u = *(const uint4*)(px + (size_t)(2 * 4 + ks) * 512);
    // xacc(0), bias-seeded
    xq[0][0] = bu4;
    xq[0][1] = br4;
    xq[0][2] = bxg4;
#pragma unroll
    for (int ks = 0; ks < 4; ++ks) {
      xq[0][0] = MFMA(wf[0][ks], x0[ks].s, xq[0][0]);
      xq[0][1] = MFMA(wf[2][ks], x0[ks].s, xq[0][1]);
      xq[0][2] = MFMA(wf[4][ks], x0[ks].s, xq[0][2]);
    }
  } else {
    float4 a = *(const float4*)hrow;  // x(0)
    uint2 u;
    u.x = pack2bf_rne(a.x, a.y);
    u.y = pack2bf_rne(a.z, a.w);
    *(uint2*)&xbuf[0][xpos] = u;
    xnext = *(const float4*)(hrow + H_);  // x(1)
  }

  // att prefetch (depth 2): one value per lane (its batch row n), L1-resident
  float ap2[2];
  const float* pa = att + (size_t)(r0 + n) * T_;
  ap2[0] = pa[0];
  ap2[1] = pa[1];

  // this lane's h state: h[row n][cols ob..ob+3]
  float hreg[4] = {0.0f, 0.0f, 0.0f, 0.0f};
  // h write-back address: 4 consecutive cols inside one swizzle granule
  const int wri = n * 128 + (((w * 2 + (q >> 1)) ^ (n & 7)) * 8) + (q & 1) * 4;
  ck_barrier();

#pragma unroll 2
  for (int t = 0; t < T_; ++t) {
    const int cur = t & 1, nxt = cur ^ 1;
    // h-frags for step t (recurrence-critical) — issue reads first
    short8 ha[4];
#pragma unroll
    for (int ks = 0; ks < 4; ++ks)
      ha[ks] = *(short8*)&hbuf[cur][n * 128 + ((ks * 4 + q) ^ (n & 7)) * 8];

    // h-side MFMA chains; ahg C-seeded with bhg (prescaled)
    f32x4 ahu = {0, 0, 0, 0}, ahr = {0, 0, 0, 0}, ahg = bhg4;
#pragma unroll
    for (int ks = 0; ks < 4; ++ks) {
      ahu = MFMA(wf[1][ks], ha[ks], ahu);
      ahr = MFMA(wf[3][ks], ha[ks], ahr);
      ahg = MFMA(wf[5][ks], ha[ks], ahg);
    }

    if constexpr (!DIRECT) {
      // fallback: x-MFMAs in-step from LDS-staged x(t)
      short8 xa[4];
#pragma unroll
      for (int ks = 0; ks < 4; ++ks)
        xa[ks] = *(short8*)&xbuf[cur][n * 128 + ((ks * 4 + q) ^ (n & 7)) * 8];
      xq[cur][0] = bu4;
      xq[cur][1] = br4;
      xq[cur][2] = bxg4;
#pragma unroll
      for (int ks = 0; ks < 4; ++ks) {
        xq[cur][0] = MFMA(wf[0][ks], xa[ks], xq[cur][0]);
        xq[cur][1] = MFMA(wf[2][ks], xa[ks], xq[cur][1]);
        xq[cur][2] = MFMA(wf[4][ks], xa[ks], xq[cur][2]);
      }
    }

    const int tp = (t + 2 < T_) ? t + 2 : T_ - 1;
    const float at = ap2[cur];
    ap2[cur] = pa[tp];

    // gates (step t) INTERLEAVED with x-side MFMA chunks (step t+1).
    // All pre-activations are prescaled by log2e (u,r) / 2*log2e (g):
    // sigmoid(s) = rcp(1 + exp2(-s')), tanh(s) = 2*rcp(1+exp2(-s')) - 1.
    float hn[4];
#pragma unroll
    for (int r = 0; r < 4; ++r) {
      const float su = xq[cur][0][r] + ahu[r];
      const float uu = at * rcp_f(1.0f + exp2_f(-su));
      const float sr = xq[cur][1][r] + ahr[r];
      const float rr = rcp_f(1.0f + exp2_f(-sr));
      const float sg = xq[cur][2][r] + rr * ahg[r];  // ahg already has +bhg
      const float g = 2.0f * rcp_f(1.0f + exp2_f(-sg)) - 1.0f;
      hn[r] = hreg[r] + uu * (g - hreg[r]);
      hreg[r] = hn[r];
      if constexpr (DIRECT) {
        const short8 xs = xp[nxt][r].s;  // frag chunk ks=r for step t+1
        xq[nxt][0] = MFMA(wf[0][r], xs, (r == 0) ? bu4 : xq[nxt][0]);
        xq[nxt][1] = MFMA(wf[2][r], xs, (r == 0) ? br4 : xq[nxt][1]);
        xq[nxt][2] = MFMA(wf[4][r], xs, (r == 0) ? bxg4 : xq[nxt][2]);
      }
    }

    // single 8B LDS write ASAP: 4 consecutive bf16 cols of row n
    uint2 up;
    up.x = pack2bf_trunc(hn[0], hn[1]);
    up.y = pack2bf_trunc(hn[2], hn[3]);
    *(uint2*)&hbuf[nxt][wri] = up;

    if constexpr (DIRECT) {
      // reload slot (t+1)&1 with frags for step t+3 (2-step lead)
      const int tf = (t + 3 < T_) ? t + 3 : T_ - 1;
#pragma unroll
      for (int ks = 0; ks < 4; ++ks)
        xp[nxt][ks].u = *(const uint4*)(px + (size_t)(tf * 4 + ks) * 512);
      // ---- T19 schedule pin for this iteration's region ----
      SGB(SG_DS_RD, 4);    // ha frags
      SGB(SG_MFMA, 12);    // h-side chains
      SGB(SG_VMEM_RD, 5);  // xp prefetch (4) + att (1)
      SGB(SG_VALU, 16);    // gate r=0
      SGB(SG_MFMA, 3);     // x-side chunk 0
      SGB(SG_VALU, 16);    // gate r=1
      SGB(SG_MFMA, 3);
      SGB(SG_VALU, 16);    // gate r=2
      SGB(SG_MFMA, 3);
      SGB(SG_VALU, 16);    // gate r=3
      SGB(SG_MFMA, 3);
      SGB(SG_VALU, 8);     // pack + misc
      SGB(SG_DS_WR, 1);    // h write-back
    } else {
      uint2 u;
      u.x = pack2bf_rne(xnext.x, xnext.y);
      u.y = pack2bf_rne(xnext.z, xnext.w);
      *(uint2*)&xbuf[nxt][xpos] = u;  // stage x(t+1)
      xnext = *(const float4*)(hrow + (size_t)tp * H_);
    }
    ck_barrier();
  }

  // final h store (hreg holds h(T-1))
  f32x4 hv = {hreg[0], hreg[1], hreg[2], hreg[3]};
  *(f32x4*)(h_out + (size_t)(r0 + n) * H_ + ob) = hv;
}

// ---------------------------------------------------------------------------
// K_D: out = [h | targets[:,0]] @ ln2_w^T + ln2_b (fp32)
// ---------------------------------------------------------------------------
__global__ __launch_bounds__(256, 4) void final_kernel(
    const float* __restrict__ tgt, const float* __restrict__ hfin,
    const float* __restrict__ w, const float* __restrict__ bias,
    float* __restrict__ out) {
  const int b = blockIdx.x, tid = threadIdx.x;
  const int o = tid >> 1, half = tid & 1;
  const float* src = half ? (tgt + (size_t)b * (T_ * H_)) : (hfin + (size_t)b * H_);
  const float* wrow = w + o * 256 + half * 128;
  float acc = 0.0f;
#pragma unroll 8
  for (int k = 0; k < 128; k += 4) {
    float4 sv = *(const float4*)(src + k);
    float4 wv = *(const float4*)(wrow + k);
    acc += sv.x * wv.x + sv.y * wv.y + sv.z * wv.z + sv.w * wv.w;
  }
  acc += __shfl_xor(acc, 1);
  if (half == 0) out[(size_t)b * H_ + o] = acc + bias[o];
}

extern "C" void kernel_launch(void* const* d_in, const int* in_sizes, int n_in,
                              void* d_out, int out_size, void* d_ws, size_t ws_size,
                              hipStream_t stream) {
  const float* targets = (const float*)d_in[0];
  const float* history = (const float*)d_in[1];
  const float* W_w = (const float*)d_in[2];
  const float* W_b = (const float*)d_in[3];
  const float* xu_w = (const float*)d_in[4];
  const float* xu_b = (const float*)d_in[5];
  const float* hu_w = (const float*)d_in[6];
  const float* hu_b = (const float*)d_in[7];
  const float* xr_w = (const float*)d_in[8];
  const float* xr_b = (const float*)d_in[9];
  const float* hr_w = (const float*)d_in[10];
  const float* hr_b = (const float*)d_in[11];
  const float* xg_w = (const float*)d_in[12];
  const float* xg_b = (const float*)d_in[13];
  const float* hg_w = (const float*)d_in[14];
  const float* hg_b = (const float*)d_in[15];
  const float* ln2_w = (const float*)d_in[16];
  const float* ln2_b = (const float*)d_in[17];
  float* out = (float*)d_out;

  float* att = (float*)d_ws;            // [B,T] f32
  float* hfin = att + (size_t)B_ * T_;  // [B,H] f32
  const size_t fixed = (size_t)B_ * T_ * 4 + (size_t)B_ * H_ * 4;
  const size_t histbf_bytes = (size_t)64 * T_ * 4 * 512 * 8 * 2;  // 52.4 MB
  short* histbf = (ws_size >= fixed + histbf_bytes)
                      ? (short*)((char*)d_ws + fixed)
                      : nullptr;

  proj_scores_kernel<<<dim3(13, 64), dim3(512), 0, stream>>>(
      targets, history, W_w, W_b, att, histbf);
  softmax_kernel<<<dim3(B_), dim3(256), 0, stream>>>(att);
  if (histbf) {
    scan3_kernel<true><<<dim3(64), dim3(512), 0, stream>>>(
        history, xu_w, xu_b, hu_w, hu_b, xr_w, xr_b, hr_w, hr_b,
        xg_w, xg_b, hg_w, hg_b, att, histbf, hfin);
  } else {
    scan3_kernel<false><<<dim3(64), dim3(512), 0, stream>>>(
        history, xu_w, xu_b, hu_w, hu_b, xr_w, xr_b, hr_w, hr_b,
        xg_w, xg_b, hg_w, hg_b, att, histbf, hfin);
  }
  final_kernel<<<dim3(B_), dim3(256), 0, stream>>>(targets, hfin, ln2_w, ln2_b, out);
}

// Round 5
// 445.887 us; speedup vs baseline: 1.1110x; 1.0094x over previous
//
#include <hip/hip_runtime.h>

#define B_ 1024
#define T_ 200
#define H_ 128
#define TSTR (T_ + 4)  // histbf padded time-stride (pad absorbs prefetch overrun)

typedef __attribute__((ext_vector_type(8))) short short8;
typedef __attribute__((ext_vector_type(4))) float f32x4;

#define MFMA(a, b, c) __builtin_amdgcn_mfma_f32_16x16x32_bf16((a), (b), (c), 0, 0, 0)

static __device__ __forceinline__ short f2bf(float f) {
  unsigned u = __float_as_uint(f);
  u += 0x7fffu + ((u >> 16) & 1u);  // RNE
  return (short)(u >> 16);
}
static __device__ __forceinline__ float bf2f(short s) {
  return __uint_as_float(((unsigned)(unsigned short)s) << 16);
}
// pack two floats as bf16 (RNE) into one dword: low short = a, high short = b
static __device__ __forceinline__ unsigned pack2bf_rne(float a, float b) {
  unsigned ua = __float_as_uint(a);
  ua += 0x7fffu + ((ua >> 16) & 1u);
  unsigned ub = __float_as_uint(b);
  ub += 0x7fffu + ((ub >> 16) & 1u);
  return (ua >> 16) | (ub & 0xFFFF0000u);
}
// truncating pack (matches previous h-state rounding)
static __device__ __forceinline__ unsigned pack2bf_trunc(float a, float b) {
  return (__float_as_uint(a) >> 16) | (__float_as_uint(b) & 0xFFFF0000u);
}
static __device__ __forceinline__ float rcp_f(float x) { return __builtin_amdgcn_rcpf(x); }
static __device__ __forceinline__ float exp2_f(float x) { return __builtin_amdgcn_exp2f(x); }
// CK-style barrier: LDS-only drain, does NOT drain vmcnt (keeps global prefetch alive)
static __device__ __forceinline__ void ck_barrier() {
  asm volatile("s_waitcnt lgkmcnt(0)\n\ts_barrier" ::: "memory");
}

// ---------------------------------------------------------------------------
// K_A: attention scores (split bf16 3-pass, fp32-grade) + hist->bf16 repack.
// v2: sp double-buffered -> ONE barrier per iteration (was two). Staging
// double-buffers were already safe under a single barrier (write into buf X
// in iter tl happens after barrier(tl); reads of buf X in iter tl were
// before barrier(tl)).
// ---------------------------------------------------------------------------
__global__ __launch_bounds__(512, 1) void proj_scores_kernel(
    const float* __restrict__ tgt, const float* __restrict__ hist,
    const float* __restrict__ Ww, const float* __restrict__ Wb,
    float* __restrict__ scores, short* __restrict__ histbf) {
  const int tc = blockIdx.x, bb = blockIdx.y;
  const int nt = (tc == 12) ? 8 : 16;
  const int t0 = tc * 16;
  const int tid = threadIdx.x;
  const int lane = tid & 63, w = tid >> 6;
  const int n = lane & 15, q = lane >> 4;

  __shared__ short tgt_hi[2][16 * 128];
  __shared__ short tgt_lo[2][16 * 128];
  __shared__ float hist_f[2][16 * 132];  // padded rows
  __shared__ float sp[2][16 * 8];

  // register A-frags for Ww (hi/lo split): A[i][k] = Ww[w*16+i][k]
  short8 whi[4], wlo[4];
  f32x4 wb4;
  {
    const int o = w * 16 + n;
#pragma unroll
    for (int ks = 0; ks < 4; ++ks) {
      const float* p = Ww + o * H_ + ks * 32 + q * 8;
      short8 h, l;
#pragma unroll
      for (int j = 0; j < 8; ++j) {
        float f = p[j];
        short hv = f2bf(f);
        h[j] = hv;
        l[j] = f2bf(f - bf2f(hv));
      }
      whi[ks] = h;
      wlo[ks] = l;
    }
    wb4 = *(const f32x4*)(Wb + w * 16 + q * 4);  // biases for this lane's 4 cols
  }

  // staging: thread -> (row sm, 4-float granule cs)
  const int sm = tid >> 5, cs = tid & 31;
  const int g = cs >> 1, half = cs & 1;
  const int spos16 = sm * 128 + ((g ^ (sm & 7)) * 8) + half * 4;  // shorts
  const int sposf = sm * 132 + cs * 4;                            // floats
  const size_t rowbase = ((size_t)(bb * 16 + sm) * T_) * H_ + cs * 4;

  // histbf conversion mapping: thread handles 8 bytes (4 shorts)
  const int cu = tid;
  const int cks = cu >> 7, crem = cu & 127, cwl = crem >> 1, chalf = crem & 1;
  const int crow = cwl & 15, ckb = cks * 32 + (cwl >> 4) * 8 + chalf * 4;

  float4 hv = *(const float4*)(hist + rowbase + (size_t)t0 * H_);
  float4 tv = *(const float4*)(tgt + rowbase + (size_t)t0 * H_);
  {
    *(float4*)&hist_f[0][sposf] = hv;
    uint2 hi, lo;
    hi.x = pack2bf_rne(tv.x, tv.y);
    hi.y = pack2bf_rne(tv.z, tv.w);
    lo.x = pack2bf_rne(tv.x - bf2f((short)(hi.x)), tv.y - bf2f((short)(hi.x >> 16)));
    lo.y = pack2bf_rne(tv.z - bf2f((short)(hi.y)), tv.w - bf2f((short)(hi.y >> 16)));
    *(uint2*)&tgt_hi[0][spos16] = hi;
    *(uint2*)&tgt_lo[0][spos16] = lo;
  }
  ck_barrier();

  for (int tl = 0; tl < nt; ++tl) {
    const int cur = tl & 1, nxt = cur ^ 1;
    const bool have_next = (tl + 1 < nt);
    if (have_next) {
      hv = *(const float4*)(hist + rowbase + (size_t)(t0 + tl + 1) * H_);
      tv = *(const float4*)(tgt + rowbase + (size_t)(t0 + tl + 1) * H_);
    }
    // scores MFMA: 3-pass split bf16, swapped operands (A = W, B = tgt)
    f32x4 s1 = {0, 0, 0, 0}, s2 = {0, 0, 0, 0}, s3 = {0, 0, 0, 0};
#pragma unroll
    for (int ks = 0; ks < 4; ++ks) {
      const int fp = n * 128 + ((ks * 4 + q) ^ (n & 7)) * 8;
      short8 ahi = *(short8*)&tgt_hi[cur][fp];
      short8 alo = *(short8*)&tgt_lo[cur][fp];
      s1 = MFMA(whi[ks], ahi, s1);
      s2 = MFMA(wlo[ks], ahi, s2);
      s3 = MFMA(whi[ks], alo, s3);
    }
    // dot with hist (fp32): lane holds (row n, cols w*16+q*4..+3)
    {
      f32x4 hv4 = *(const f32x4*)&hist_f[cur][n * 132 + w * 16 + q * 4];
      float v = (s1[0] + s2[0] + s3[0] + wb4[0]) * hv4[0];
      v += (s1[1] + s2[1] + s3[1] + wb4[1]) * hv4[1];
      v += (s1[2] + s2[2] + s3[2] + wb4[2]) * hv4[2];
      v += (s1[3] + s2[3] + s3[3] + wb4[3]) * hv4[3];
      v += __shfl_xor(v, 16);
      v += __shfl_xor(v, 32);
      if (lane < 16) sp[cur][n * 8 + w] = v;
    }
    // hist -> bf16 packed global (scan-native layout, TSTR stride)
    if (histbf != nullptr) {
      const float* src = &hist_f[cur][crow * 132 + ckb];
      uint2 u;
      u.x = pack2bf_rne(src[0], src[1]);
      u.y = pack2bf_rne(src[2], src[3]);
      const size_t sb =
          (((size_t)(bb * TSTR + t0 + tl) * 4) + cks) * 512 + cwl * 8 + chalf * 4;
      *(uint2*)(histbf + sb) = u;
    }
    // stage next tile (prefetched regs)
    if (have_next) {
      *(float4*)&hist_f[nxt][sposf] = hv;
      uint2 hi, lo;
      hi.x = pack2bf_rne(tv.x, tv.y);
      hi.y = pack2bf_rne(tv.z, tv.w);
      lo.x = pack2bf_rne(tv.x - bf2f((short)(hi.x)), tv.y - bf2f((short)(hi.x >> 16)));
      lo.y = pack2bf_rne(tv.z - bf2f((short)(hi.y)), tv.w - bf2f((short)(hi.y >> 16)));
      *(uint2*)&tgt_hi[nxt][spos16] = hi;
      *(uint2*)&tgt_lo[nxt][spos16] = lo;
    }
    ck_barrier();
    // finish scores for THIS iter (reads sp[cur]; next iter writes sp[nxt])
    if (tid < 16) {
      float s = 0.0f;
#pragma unroll
      for (int ww = 0; ww < 8; ++ww) s += sp[cur][tid * 8 + ww];
      scores[(size_t)(bb * 16 + tid) * T_ + (t0 + tl)] = s;
    }
  }
}

// ---------------------------------------------------------------------------
// K_B: softmax over T, in place. One block per batch row.
// ---------------------------------------------------------------------------
__global__ __launch_bounds__(256, 4) void softmax_kernel(float* __restrict__ att) {
  const int b = blockIdx.x, tid = threadIdx.x;
  const int lane = tid & 63, wave = tid >> 6;
  __shared__ float red[8];
  float v = (tid < T_) ? att[(size_t)b * T_ + tid] : -3.0e38f;
  float mx = v;
#pragma unroll
  for (int d = 1; d < 64; d <<= 1) mx = fmaxf(mx, __shfl_xor(mx, d));
  if (lane == 0) red[wave] = mx;
  __syncthreads();
  mx = fmaxf(fmaxf(red[0], red[1]), fmaxf(red[2], red[3]));
  float e = (tid < T_) ? __expf(v - mx) : 0.0f;
  float sm = e;
#pragma unroll
  for (int d = 1; d < 64; d <<= 1) sm += __shfl_xor(sm, d);
  if (lane == 0) red[4 + wave] = sm;
  __syncthreads();
  sm = red[4] + red[5] + red[6] + red[7];
  if (tid < T_) att[(size_t)b * T_ + tid] = e / sm;
}

// ---------------------------------------------------------------------------
// K_C: recurrent scan v8. Model (R2-R4 counters): step = MFMA + VALU + sync,
// strictly additive — MFMA and VALU share the SIMD datapath on CDNA4, so
// overlap is impossible; the only lever is TOTAL op count. v8 removes VALU:
//  - h-side MFMA chains C-seeded with x-side accumulators (su/sr adds and
//    half the acc reads gone); x-chains C-seeded with biases (no seed movs).
//  - att: one f32x4 load per 4 steps, 2 buffers, 8-step lead; explicit
//    tb+=8 outer loop + fully unrolled k inner loop so all t-masks fold.
//  - xp prefetch: pure pointer increment into TSTR-padded histbf (no mul,
//    no clamp select; pad rows feed throwaway MFMAs for steps >= T).
// ---------------------------------------------------------------------------
template <bool DIRECT>
__global__ __launch_bounds__(512, 1) void scan3_kernel(
    const float* __restrict__ hist,
    const float* __restrict__ xu_w, const float* __restrict__ xu_b,
    const float* __restrict__ hu_w, const float* __restrict__ hu_b,
    const float* __restrict__ xr_w, const float* __restrict__ xr_b,
    const float* __restrict__ hr_w, const float* __restrict__ hr_b,
    const float* __restrict__ xg_w, const float* __restrict__ xg_b,
    const float* __restrict__ hg_w, const float* __restrict__ hg_b,
    const float* __restrict__ att, const short* __restrict__ histbf,
    float* __restrict__ h_out) {
  const int tid = threadIdx.x;
  const int lane = tid & 63, w = tid >> 6;
  const int n = lane & 15, q = lane >> 4;
  const int bb = blockIdx.x, r0 = bb * 16;
  const int o = w * 16 + n;       // A-frag packing index (W rows = output cols)
  const int ob = w * 16 + q * 4;  // this lane's 4 output cols (D layout)

  constexpr float LOG2E = 1.4426950408889634f;

  __shared__ short hbuf[2][16 * 128];
  __shared__ short xbuf[2][16 * 128];  // only used when !DIRECT

  // A-frags: 0=xu 1=hu 2=xr 3=hr 4=xg 5=hg  (96 VGPRs)
  // exp2-prescaled: u/r rows by log2e, g rows by 2*log2e.
  short8 wf[6][4];
  {
    const float* Wm[6] = {xu_w, hu_w, xr_w, hr_w, xg_w, hg_w};
    const float Sc[6] = {LOG2E, LOG2E, LOG2E, LOG2E, 2.0f * LOG2E, 2.0f * LOG2E};
#pragma unroll
    for (int M = 0; M < 6; ++M)
#pragma unroll
      for (int ks = 0; ks < 4; ++ks) {
        const float* p = Wm[M] + o * H_ + ks * 32 + q * 8;
        short8 v;
#pragma unroll
        for (int j = 0; j < 8; ++j) v[j] = f2bf(p[j] * Sc[M]);
        wf[M][ks] = v;
      }
  }
  // biases for this lane's 4 output cols, same prescale
  const f32x4 bu4 = (*(const f32x4*)(xu_b + ob) + *(const f32x4*)(hu_b + ob)) * LOG2E;
  const f32x4 br4 = (*(const f32x4*)(xr_b + ob) + *(const f32x4*)(hr_b + ob)) * LOG2E;
  const f32x4 bxg4 = *(const f32x4*)(xg_b + ob) * (2.0f * LOG2E);
  const f32x4 bhg4 = *(const f32x4*)(hg_b + ob) * (2.0f * LOG2E);

  for (int i = tid; i < 16 * 128; i += 512) hbuf[0][i] = 0;

  // --- x-fragment prefetch state ---
  typedef union { uint4 u; short8 s; } frag_u;
  frag_u xp[2][4];  // xp[f&1] holds x-frags for step f (DIRECT path)
  const short* px = histbf + ((size_t)bb * TSTR * 4) * 512 + (size_t)lane * 8;
  // --- fallback staging state ---
  const int sm = tid >> 5, cs = tid & 31;
  const int xpos = sm * 128 + (((cs >> 1) ^ (sm & 7)) * 8) + (cs & 1) * 4;
  const float* hrow = hist + ((size_t)(r0 + sm) * T_) * H_ + cs * 4;
  float4 xnext;

  // x-accumulators: xq[t&1] = {xu,xr,xg} partials for step t (bias-seeded).
  f32x4 xq[2][3];

  if constexpr (DIRECT) {
    frag_u x0[4];
#pragma unroll
    for (int ks = 0; ks < 4; ++ks)
      x0[ks].u = *(const uint4*)(px + (size_t)(0 * 4 + ks) * 512);
#pragma unroll
    for (int ks = 0; ks < 4; ++ks)
      xp[1][ks].u = *(const uint4*)(px + (size_t)(1 * 4 + ks) * 512);
#pragma unroll
    for (int ks = 0; ks < 4; ++ks)
      xp[0][ks].u = *(const uint4*)(px + (size_t)(2 * 4 + ks) * 512);
    // xacc(0): first MFMA takes bias as C directly
    xq[0][0] = MFMA(wf[0][0], x0[0].s, bu4);
    xq[0][1] = MFMA(wf[2][0], x0[0].s, br4);
    xq[0][2] = MFMA(wf[4][0], x0[0].s, bxg4);
#pragma unroll
    for (int ks = 1; ks < 4; ++ks) {
      xq[0][0] = MFMA(wf[0][ks], x0[ks].s, xq[0][0]);
      xq[0][1] = MFMA(wf[2][ks], x0[ks].s, xq[0][1]);
      xq[0][2] = MFMA(wf[4][ks], x0[ks].s, xq[0][2]);
    }
  } else {
    float4 a = *(const float4*)hrow;  // x(0)
    uint2 u;
    u.x = pack2bf_rne(a.x, a.y);
    u.y = pack2bf_rne(a.z, a.w);
    *(uint2*)&xbuf[0][xpos] = u;
    xnext = *(const float4*)(hrow + H_);  // x(1)
  }

  // att: one f32x4 per 4 steps, 2 buffers, 8-step lead. Row base is 800B
  // aligned, t%4 offsets are 16B aligned.
  const float* pa = att + (size_t)(r0 + n) * T_;
  f32x4 ab0 = *(const f32x4*)(pa + 0);  // t = 0..3
  f32x4 ab1 = *(const f32x4*)(pa + 4);  // t = 4..7

  // this lane's h state: h[row n][cols ob..ob+3]
  float hreg[4] = {0.0f, 0.0f, 0.0f, 0.0f};
  // h write-back address: 4 consecutive cols inside one swizzle granule
  const int wri = n * 128 + (((w * 2 + (q >> 1)) ^ (n & 7)) * 8) + (q & 1) * 4;
  ck_barrier();

  if constexpr (DIRECT) {
    const short* pxt = px + (size_t)12 * 512;  // frags for step 3 (t+3 at t=0)
    for (int tb = 0; tb < T_; tb += 8) {       // 200 = 25 * 8
#pragma unroll
      for (int k = 0; k < 8; ++k) {
        const int t = tb + k;
        const int cur = k & 1, nxt = cur ^ 1;
        // h-frags for step t (recurrence-critical)
        short8 ha[4];
#pragma unroll
        for (int ks = 0; ks < 4; ++ks)
          ha[ks] = *(short8*)&hbuf[cur][n * 128 + ((ks * 4 + q) ^ (n & 7)) * 8];

        // h-side chains C-SEEDED with x-side accumulators (u,r) / bias (g):
        // gate pre-activations come out complete — no adds, half the reads.
        f32x4 ahu = MFMA(wf[1][0], ha[0], xq[cur][0]);
        f32x4 ahr = MFMA(wf[3][0], ha[0], xq[cur][1]);
        f32x4 ahg = MFMA(wf[5][0], ha[0], bhg4);
#pragma unroll
        for (int ks = 1; ks < 4; ++ks) {
          ahu = MFMA(wf[1][ks], ha[ks], ahu);
          ahr = MFMA(wf[3][ks], ha[ks], ahr);
          ahg = MFMA(wf[5][ks], ha[ks], ahg);
        }

        // x-side for step t+1 (bias as C of first chunk, no seed movs)
        {
          const short8 x0s = xp[nxt][0].s;
          xq[nxt][0] = MFMA(wf[0][0], x0s, bu4);
          xq[nxt][1] = MFMA(wf[2][0], x0s, br4);
          xq[nxt][2] = MFMA(wf[4][0], x0s, bxg4);
#pragma unroll
          for (int ks = 1; ks < 4; ++ks) {
            const short8 xs = xp[nxt][ks].s;
            xq[nxt][0] = MFMA(wf[0][ks], xs, xq[nxt][0]);
            xq[nxt][1] = MFMA(wf[2][ks], xs, xq[nxt][1]);
            xq[nxt][2] = MFMA(wf[4][ks], xs, xq[nxt][2]);
          }
        }
        // reload slot nxt with frags for step t+3 (pure pointer walk; pads
        // beyond T feed throwaway MFMAs whose results are never used)
#pragma unroll
        for (int ks = 0; ks < 4; ++ks)
          xp[nxt][ks].u = *(const uint4*)(pxt + (size_t)(k * 4 + ks) * 512);

        // att for this step (all masks fold to literals: tb % 8 == 0)
        const float at = ((k >> 2) & 1) ? ab1[k & 3] : ab0[k & 3];
        if (k == 3) ab0 = *(const f32x4*)(pa + ((t + 5 <= T_ - 4) ? t + 5 : T_ - 4));
        if (k == 7) ab1 = *(const f32x4*)(pa + ((t + 5 <= T_ - 4) ? t + 5 : T_ - 4));

        // gates: pre-activations are complete and exp2-prescaled
        float hn[4];
#pragma unroll
        for (int r = 0; r < 4; ++r) {
          const float uu = at * rcp_f(1.0f + exp2_f(-ahu[r]));
          const float rr = rcp_f(1.0f + exp2_f(-ahr[r]));
          const float sg = xq[cur][2][r] + rr * ahg[r];
          const float g = 2.0f * rcp_f(1.0f + exp2_f(-sg)) - 1.0f;
          hn[r] = hreg[r] + uu * (g - hreg[r]);
          hreg[r] = hn[r];
        }

        // single 8B LDS write: 4 consecutive bf16 cols of row n
        uint2 up;
        up.x = pack2bf_trunc(hn[0], hn[1]);
        up.y = pack2bf_trunc(hn[2], hn[3]);
        *(uint2*)&hbuf[nxt][wri] = up;
        ck_barrier();
      }
      pxt += (size_t)8 * 4 * 512;
    }
  } else {
    // fallback: LDS-staged x path (unchanged structure)
#pragma unroll 2
    for (int t = 0; t < T_; ++t) {
      const int cur = t & 1, nxt = cur ^ 1;
      short8 ha[4];
#pragma unroll
      for (int ks = 0; ks < 4; ++ks)
        ha[ks] = *(short8*)&hbuf[cur][n * 128 + ((ks * 4 + q) ^ (n & 7)) * 8];
      short8 xa[4];
#pragma unroll
      for (int ks = 0; ks < 4; ++ks)
        xa[ks] = *(short8*)&xbuf[cur][n * 128 + ((ks * 4 + q) ^ (n & 7)) * 8];
      // x-side first, then h-side seeded with it
      f32x4 xu_a = MFMA(wf[0][0], xa[0], bu4);
      f32x4 xr_a = MFMA(wf[2][0], xa[0], br4);
      f32x4 xg_a = MFMA(wf[4][0], xa[0], bxg4);
#pragma unroll
      for (int ks = 1; ks < 4; ++ks) {
        xu_a = MFMA(wf[0][ks], xa[ks], xu_a);
        xr_a = MFMA(wf[2][ks], xa[ks], xr_a);
        xg_a = MFMA(wf[4][ks], xa[ks], xg_a);
      }
      f32x4 ahu = MFMA(wf[1][0], ha[0], xu_a);
      f32x4 ahr = MFMA(wf[3][0], ha[0], xr_a);
      f32x4 ahg = MFMA(wf[5][0], ha[0], bhg4);
#pragma unroll
      for (int ks = 1; ks < 4; ++ks) {
        ahu = MFMA(wf[1][ks], ha[ks], ahu);
        ahr = MFMA(wf[3][ks], ha[ks], ahr);
        ahg = MFMA(wf[5][ks], ha[ks], ahg);
      }
      const int tp = (t + 2 < T_) ? t + 2 : T_ - 1;
      const float at = ((t >> 2) & 1) ? ab1[t & 3] : ab0[t & 3];
      if ((t & 7) == 3) ab0 = *(const f32x4*)(pa + ((t + 5 <= T_ - 4) ? t + 5 : T_ - 4));
      if ((t & 7) == 7) ab1 = *(const f32x4*)(pa + ((t + 5 <= T_ - 4) ? t + 5 : T_ - 4));
      float hn[4];
#pragma unroll
      for (int r = 0; r < 4; ++r) {
        const float uu = at * rcp_f(1.0f + exp2_f(-ahu[r]));
        const float rr = rcp_f(1.0f + exp2_f(-ahr[r]));
        const float sg = xg_a[r] + rr * ahg[r];
        const float g = 2.0f * rcp_f(1.0f + exp2_f(-sg)) - 1.0f;
        hn[r] = hreg[r] + uu * (g - hreg[r]);
        hreg[r] = hn[r];
      }
      uint2 up;
      up.x = pack2bf_trunc(hn[0], hn[1]);
      up.y = pack2bf_trunc(hn[2], hn[3]);
      *(uint2*)&hbuf[nxt][wri] = up;
      uint2 u;
      u.x = pack2bf_rne(xnext.x, xnext.y);
      u.y = pack2bf_rne(xnext.z, xnext.w);
      *(uint2*)&xbuf[nxt][xpos] = u;  // stage x(t+1)
      xnext = *(const float4*)(hrow + (size_t)tp * H_);
      ck_barrier();
    }
  }

  // final h store (hreg holds h(T-1))
  f32x4 hv = {hreg[0], hreg[1], hreg[2], hreg[3]};
  *(f32x4*)(h_out + (size_t)(r0 + n) * H_ + ob) = hv;
}

// ---------------------------------------------------------------------------
// K_D: out = [h | targets[:,0]] @ ln2_w^T + ln2_b (fp32)
// ---------------------------------------------------------------------------
__global__ __launch_bounds__(256, 4) void final_kernel(
    const float* __restrict__ tgt, const float* __restrict__ hfin,
    const float* __restrict__ w, const float* __restrict__ bias,
    float* __restrict__ out) {
  const int b = blockIdx.x, tid = threadIdx.x;
  const int o = tid >> 1, half = tid & 1;
  const float* src = half ? (tgt + (size_t)b * (T_ * H_)) : (hfin + (size_t)b * H_);
  const float* wrow = w + o * 256 + half * 128;
  float acc = 0.0f;
#pragma unroll 8
  for (int k = 0; k < 128; k += 4) {
    float4 sv = *(const float4*)(src + k);
    float4 wv = *(const float4*)(wrow + k);
    acc += sv.x * wv.x + sv.y * wv.y + sv.z * wv.z + sv.w * wv.w;
  }
  acc += __shfl_xor(acc, 1);
  if (half == 0) out[(size_t)b * H_ + o] = acc + bias[o];
}

extern "C" void kernel_launch(void* const* d_in, const int* in_sizes, int n_in,
                              void* d_out, int out_size, void* d_ws, size_t ws_size,
                              hipStream_t stream) {
  const float* targets = (const float*)d_in[0];
  const float* history = (const float*)d_in[1];
  const float* W_w = (const float*)d_in[2];
  const float* W_b = (const float*)d_in[3];
  const float* xu_w = (const float*)d_in[4];
  const float* xu_b = (const float*)d_in[5];
  const float* hu_w = (const float*)d_in[6];
  const float* hu_b = (const float*)d_in[7];
  const float* xr_w = (const float*)d_in[8];
  const float* xr_b = (const float*)d_in[9];
  const float* hr_w = (const float*)d_in[10];
  const float* hr_b = (const float*)d_in[11];
  const float* xg_w = (const float*)d_in[12];
  const float* xg_b = (const float*)d_in[13];
  const float* hg_w = (const float*)d_in[14];
  const float* hg_b = (const float*)d_in[15];
  const float* ln2_w = (const float*)d_in[16];
  const float* ln2_b = (const float*)d_in[17];
  float* out = (float*)d_out;

  float* att = (float*)d_ws;            // [B,T] f32
  float* hfin = att + (size_t)B_ * T_;  // [B,H] f32
  const size_t fixed = (size_t)B_ * T_ * 4 + (size_t)B_ * H_ * 4;
  const size_t histbf_bytes = (size_t)64 * TSTR * 4 * 512 * 2;  // 53.5 MB
  short* histbf = (ws_size >= fixed + histbf_bytes)
                      ? (short*)((char*)d_ws + fixed)
                      : nullptr;

  proj_scores_kernel<<<dim3(13, 64), dim3(512), 0, stream>>>(
      targets, history, W_w, W_b, att, histbf);
  softmax_kernel<<<dim3(B_), dim3(256), 0, stream>>>(att);
  if (histbf) {
    scan3_kernel<true><<<dim3(64), dim3(512), 0, stream>>>(
        history, xu_w, xu_b, hu_w, hu_b, xr_w, xr_b, hr_w, hr_b,
        xg_w, xg_b, hg_w, hg_b, att, histbf, hfin);
  } else {
    scan3_kernel<false><<<dim3(64), dim3(512), 0, stream>>>(
        history, xu_w, xu_b, hu_w, hu_b, xr_w, xr_b, hr_w, hr_b,
        xg_w, xg_b, hg_w, hg_b, att, histbf, hfin);
  }
  final_kernel<<<dim3(B_), dim3(256), 0, stream>>>(targets, hfin, ln2_w, ln2_b, out);
}

// Round 6
// 434.083 us; speedup vs baseline: 1.1412x; 1.0272x over previous
//
#include <hip/hip_runtime.h>

#define B_ 1024
#define T_ 200
#define H_ 128
#define TSTR (T_ + 4)  // histbf padded time-stride (pad absorbs prefetch overrun)

typedef __attribute__((ext_vector_type(8))) short short8;
typedef __attribute__((ext_vector_type(4))) float f32x4;

#define MFMA(a, b, c) __builtin_amdgcn_mfma_f32_16x16x32_bf16((a), (b), (c), 0, 0, 0)

static __device__ __forceinline__ short f2bf(float f) {
  unsigned u = __float_as_uint(f);
  u += 0x7fffu + ((u >> 16) & 1u);  // RNE
  return (short)(u >> 16);
}
static __device__ __forceinline__ float bf2f(short s) {
  return __uint_as_float(((unsigned)(unsigned short)s) << 16);
}
// pack two floats as bf16 (RNE) into one dword: low short = a, high short = b
static __device__ __forceinline__ unsigned pack2bf_rne(float a, float b) {
  unsigned ua = __float_as_uint(a);
  ua += 0x7fffu + ((ua >> 16) & 1u);
  unsigned ub = __float_as_uint(b);
  ub += 0x7fffu + ((ub >> 16) & 1u);
  return (ua >> 16) | (ub & 0xFFFF0000u);
}
// truncating pack via one v_perm_b32: dst = [b.hi16 | a.hi16]
static __device__ __forceinline__ unsigned pack2bf_trunc(float a, float b) {
  return __builtin_amdgcn_perm(__float_as_uint(b), __float_as_uint(a), 0x07060302u);
}
static __device__ __forceinline__ float rcp_f(float x) { return __builtin_amdgcn_rcpf(x); }
static __device__ __forceinline__ float exp2_f(float x) { return __builtin_amdgcn_exp2f(x); }
// CK-style barrier: LDS-only drain, does NOT drain vmcnt (keeps global prefetch alive)
static __device__ __forceinline__ void ck_barrier() {
  asm volatile("s_waitcnt lgkmcnt(0)\n\ts_barrier" ::: "memory");
}

// ---------------------------------------------------------------------------
// K_A: attention scores (split bf16 3-pass, fp32-grade) + hist->bf16 repack.
// (unchanged from R5: single barrier per iteration, TSTR-padded histbf)
// ---------------------------------------------------------------------------
__global__ __launch_bounds__(512, 1) void proj_scores_kernel(
    const float* __restrict__ tgt, const float* __restrict__ hist,
    const float* __restrict__ Ww, const float* __restrict__ Wb,
    float* __restrict__ scores, short* __restrict__ histbf) {
  const int tc = blockIdx.x, bb = blockIdx.y;
  const int nt = (tc == 12) ? 8 : 16;
  const int t0 = tc * 16;
  const int tid = threadIdx.x;
  const int lane = tid & 63, w = tid >> 6;
  const int n = lane & 15, q = lane >> 4;

  __shared__ short tgt_hi[2][16 * 128];
  __shared__ short tgt_lo[2][16 * 128];
  __shared__ float hist_f[2][16 * 132];  // padded rows
  __shared__ float sp[2][16 * 8];

  // register A-frags for Ww (hi/lo split): A[i][k] = Ww[w*16+i][k]
  short8 whi[4], wlo[4];
  f32x4 wb4;
  {
    const int o = w * 16 + n;
#pragma unroll
    for (int ks = 0; ks < 4; ++ks) {
      const float* p = Ww + o * H_ + ks * 32 + q * 8;
      short8 h, l;
#pragma unroll
      for (int j = 0; j < 8; ++j) {
        float f = p[j];
        short hv = f2bf(f);
        h[j] = hv;
        l[j] = f2bf(f - bf2f(hv));
      }
      whi[ks] = h;
      wlo[ks] = l;
    }
    wb4 = *(const f32x4*)(Wb + w * 16 + q * 4);  // biases for this lane's 4 cols
  }

  // staging: thread -> (row sm, 4-float granule cs)
  const int sm = tid >> 5, cs = tid & 31;
  const int g = cs >> 1, half = cs & 1;
  const int spos16 = sm * 128 + ((g ^ (sm & 7)) * 8) + half * 4;  // shorts
  const int sposf = sm * 132 + cs * 4;                            // floats
  const size_t rowbase = ((size_t)(bb * 16 + sm) * T_) * H_ + cs * 4;

  // histbf conversion mapping: thread handles 8 bytes (4 shorts)
  const int cu = tid;
  const int cks = cu >> 7, crem = cu & 127, cwl = crem >> 1, chalf = crem & 1;
  const int crow = cwl & 15, ckb = cks * 32 + (cwl >> 4) * 8 + chalf * 4;

  float4 hv = *(const float4*)(hist + rowbase + (size_t)t0 * H_);
  float4 tv = *(const float4*)(tgt + rowbase + (size_t)t0 * H_);
  {
    *(float4*)&hist_f[0][sposf] = hv;
    uint2 hi, lo;
    hi.x = pack2bf_rne(tv.x, tv.y);
    hi.y = pack2bf_rne(tv.z, tv.w);
    lo.x = pack2bf_rne(tv.x - bf2f((short)(hi.x)), tv.y - bf2f((short)(hi.x >> 16)));
    lo.y = pack2bf_rne(tv.z - bf2f((short)(hi.y)), tv.w - bf2f((short)(hi.y >> 16)));
    *(uint2*)&tgt_hi[0][spos16] = hi;
    *(uint2*)&tgt_lo[0][spos16] = lo;
  }
  ck_barrier();

  for (int tl = 0; tl < nt; ++tl) {
    const int cur = tl & 1, nxt = cur ^ 1;
    const bool have_next = (tl + 1 < nt);
    if (have_next) {
      hv = *(const float4*)(hist + rowbase + (size_t)(t0 + tl + 1) * H_);
      tv = *(const float4*)(tgt + rowbase + (size_t)(t0 + tl + 1) * H_);
    }
    // scores MFMA: 3-pass split bf16, swapped operands (A = W, B = tgt)
    f32x4 s1 = {0, 0, 0, 0}, s2 = {0, 0, 0, 0}, s3 = {0, 0, 0, 0};
#pragma unroll
    for (int ks = 0; ks < 4; ++ks) {
      const int fp = n * 128 + ((ks * 4 + q) ^ (n & 7)) * 8;
      short8 ahi = *(short8*)&tgt_hi[cur][fp];
      short8 alo = *(short8*)&tgt_lo[cur][fp];
      s1 = MFMA(whi[ks], ahi, s1);
      s2 = MFMA(wlo[ks], ahi, s2);
      s3 = MFMA(whi[ks], alo, s3);
    }
    // dot with hist (fp32): lane holds (row n, cols w*16+q*4..+3)
    {
      f32x4 hv4 = *(const f32x4*)&hist_f[cur][n * 132 + w * 16 + q * 4];
      float v = (s1[0] + s2[0] + s3[0] + wb4[0]) * hv4[0];
      v += (s1[1] + s2[1] + s3[1] + wb4[1]) * hv4[1];
      v += (s1[2] + s2[2] + s3[2] + wb4[2]) * hv4[2];
      v += (s1[3] + s2[3] + s3[3] + wb4[3]) * hv4[3];
      v += __shfl_xor(v, 16);
      v += __shfl_xor(v, 32);
      if (lane < 16) sp[cur][n * 8 + w] = v;
    }
    // hist -> bf16 packed global (scan-native layout, TSTR stride)
    if (histbf != nullptr) {
      const float* src = &hist_f[cur][crow * 132 + ckb];
      uint2 u;
      u.x = pack2bf_rne(src[0], src[1]);
      u.y = pack2bf_rne(src[2], src[3]);
      const size_t sb =
          (((size_t)(bb * TSTR + t0 + tl) * 4) + cks) * 512 + cwl * 8 + chalf * 4;
      *(uint2*)(histbf + sb) = u;
    }
    // stage next tile (prefetched regs)
    if (have_next) {
      *(float4*)&hist_f[nxt][sposf] = hv;
      uint2 hi, lo;
      hi.x = pack2bf_rne(tv.x, tv.y);
      hi.y = pack2bf_rne(tv.z, tv.w);
      lo.x = pack2bf_rne(tv.x - bf2f((short)(hi.x)), tv.y - bf2f((short)(hi.x >> 16)));
      lo.y = pack2bf_rne(tv.z - bf2f((short)(hi.y)), tv.w - bf2f((short)(hi.y >> 16)));
      *(uint2*)&tgt_hi[nxt][spos16] = hi;
      *(uint2*)&tgt_lo[nxt][spos16] = lo;
    }
    ck_barrier();
    // finish scores for THIS iter (reads sp[cur]; next iter writes sp[nxt])
    if (tid < 16) {
      float s = 0.0f;
#pragma unroll
      for (int ww = 0; ww < 8; ++ww) s += sp[cur][tid * 8 + ww];
      scores[(size_t)(bb * 16 + tid) * T_ + (t0 + tl)] = s;
    }
  }
}

// ---------------------------------------------------------------------------
// K_C: recurrent scan v9. Model (R2-R5, holds to 2%): step = MFMA + VALU +
// sync, strictly additive (MFMA/VALU share SIMD issue). v9:
//  - SOFTMAX FUSED into prologue (separate kernel + att round-trip removed):
//    16 rows x 32 threads, shfl-reduce, exp2 path, result in LDS
//    (stride 204 floats -> 8-bank spread, ~2-way = free).
//  - x-MFMA cluster issued BEFORE h-MFMA cluster: 12 register-only MFMAs
//    cover the post-barrier ds_read(ha) ~120-cyc latency.
//  - pack2bf_trunc via one v_perm_b32 (was 3 VALU ops).
// ---------------------------------------------------------------------------
template <bool DIRECT>
__global__ __launch_bounds__(512, 1) void scan3_kernel(
    const float* __restrict__ hist,
    const float* __restrict__ xu_w, const float* __restrict__ xu_b,
    const float* __restrict__ hu_w, const float* __restrict__ hu_b,
    const float* __restrict__ xr_w, const float* __restrict__ xr_b,
    const float* __restrict__ hr_w, const float* __restrict__ hr_b,
    const float* __restrict__ xg_w, const float* __restrict__ xg_b,
    const float* __restrict__ hg_w, const float* __restrict__ hg_b,
    const float* __restrict__ att_g, const short* __restrict__ histbf,
    float* __restrict__ h_out) {
  const int tid = threadIdx.x;
  const int lane = tid & 63, w = tid >> 6;
  const int n = lane & 15, q = lane >> 4;
  const int bb = blockIdx.x, r0 = bb * 16;
  const int o = w * 16 + n;       // A-frag packing index (W rows = output cols)
  const int ob = w * 16 + q * 4;  // this lane's 4 output cols (D layout)

  constexpr float LOG2E = 1.4426950408889634f;

  __shared__ short hbuf[2][16 * 128];
  __shared__ short xbuf[2][16 * 128];  // only used when !DIRECT (else dead)
  __shared__ float att_lds[16 * 204];  // softmax result; stride 204 = pad

  // A-frags: 0=xu 1=hu 2=xr 3=hr 4=xg 5=hg  (96 VGPRs)
  // exp2-prescaled: u/r rows by log2e, g rows by 2*log2e.
  short8 wf[6][4];
  {
    const float* Wm[6] = {xu_w, hu_w, xr_w, hr_w, xg_w, hg_w};
    const float Sc[6] = {LOG2E, LOG2E, LOG2E, LOG2E, 2.0f * LOG2E, 2.0f * LOG2E};
#pragma unroll
    for (int M = 0; M < 6; ++M)
#pragma unroll
      for (int ks = 0; ks < 4; ++ks) {
        const float* p = Wm[M] + o * H_ + ks * 32 + q * 8;
        short8 v;
#pragma unroll
        for (int j = 0; j < 8; ++j) v[j] = f2bf(p[j] * Sc[M]);
        wf[M][ks] = v;
      }
  }
  // biases for this lane's 4 output cols, same prescale
  const f32x4 bu4 = (*(const f32x4*)(xu_b + ob) + *(const f32x4*)(hu_b + ob)) * LOG2E;
  const f32x4 br4 = (*(const f32x4*)(xr_b + ob) + *(const f32x4*)(hr_b + ob)) * LOG2E;
  const f32x4 bxg4 = *(const f32x4*)(xg_b + ob) * (2.0f * LOG2E);
  const f32x4 bhg4 = *(const f32x4*)(hg_b + ob) * (2.0f * LOG2E);

  for (int i = tid; i < 16 * 128; i += 512) hbuf[0][i] = 0;

  // ---- fused softmax over T for this block's 16 rows -> att_lds ----
  {
    const int row = tid >> 5, idx = tid & 31;
    const float* srow = att_g + (size_t)(r0 + row) * T_;
    float v[7];
    float mx = -3.0e38f;
#pragma unroll
    for (int i = 0; i < 7; ++i) {
      const int t = idx + i * 32;
      v[i] = (t < T_) ? srow[t] : -3.0e38f;
      mx = fmaxf(mx, v[i]);
    }
#pragma unroll
    for (int d = 1; d < 32; d <<= 1) mx = fmaxf(mx, __shfl_xor(mx, d));
    float sm = 0.0f;
#pragma unroll
    for (int i = 0; i < 7; ++i) {
      v[i] = exp2_f((v[i] - mx) * LOG2E);  // t>=T: exp2(-huge)=0
      sm += v[i];
    }
#pragma unroll
    for (int d = 1; d < 32; d <<= 1) sm += __shfl_xor(sm, d);
    const float rs = rcp_f(sm);
#pragma unroll
    for (int i = 0; i < 7; ++i) {
      const int t = idx + i * 32;
      if (t < T_) att_lds[row * 204 + t] = v[i] * rs;
    }
  }

  // --- x-fragment prefetch state ---
  typedef union { uint4 u; short8 s; } frag_u;
  frag_u xp[2][4];  // xp[f&1] holds x-frags for step f (DIRECT path)
  const short* px = histbf + ((size_t)bb * TSTR * 4) * 512 + (size_t)lane * 8;
  // --- fallback staging state ---
  const int sm_ = tid >> 5, cs = tid & 31;
  const int xpos = sm_ * 128 + (((cs >> 1) ^ (sm_ & 7)) * 8) + (cs & 1) * 4;
  const float* hrow = hist + ((size_t)(r0 + sm_) * T_) * H_ + cs * 4;
  float4 xnext;

  // x-accumulators: xq[t&1] = {xu,xr,xg} partials for step t (bias-seeded).
  f32x4 xq[2][3];

  if constexpr (DIRECT) {
    frag_u x0[4];
#pragma unroll
    for (int ks = 0; ks < 4; ++ks)
      x0[ks].u = *(const uint4*)(px + (size_t)(0 * 4 + ks) * 512);
#pragma unroll
    for (int ks = 0; ks < 4; ++ks)
      xp[1][ks].u = *(const uint4*)(px + (size_t)(1 * 4 + ks) * 512);
#pragma unroll
    for (int ks = 0; ks < 4; ++ks)
      xp[0][ks].u = *(const uint4*)(px + (size_t)(2 * 4 + ks) * 512);
    // xacc(0): first MFMA takes bias as C directly
    xq[0][0] = MFMA(wf[0][0], x0[0].s, bu4);
    xq[0][1] = MFMA(wf[2][0], x0[0].s, br4);
    xq[0][2] = MFMA(wf[4][0], x0[0].s, bxg4);
#pragma unroll
    for (int ks = 1; ks < 4; ++ks) {
      xq[0][0] = MFMA(wf[0][ks], x0[ks].s, xq[0][0]);
      xq[0][1] = MFMA(wf[2][ks], x0[ks].s, xq[0][1]);
      xq[0][2] = MFMA(wf[4][ks], x0[ks].s, xq[0][2]);
    }
  } else {
    float4 a = *(const float4*)hrow;  // x(0)
    uint2 u;
    u.x = pack2bf_rne(a.x, a.y);
    u.y = pack2bf_rne(a.z, a.w);
    *(uint2*)&xbuf[0][xpos] = u;
    xnext = *(const float4*)(hrow + H_);  // x(1)
  }

  // this lane's h state: h[row n][cols ob..ob+3]
  float hreg[4] = {0.0f, 0.0f, 0.0f, 0.0f};
  // h write-back address: 4 consecutive cols inside one swizzle granule
  const int wri = n * 128 + (((w * 2 + (q >> 1)) ^ (n & 7)) * 8) + (q & 1) * 4;
  ck_barrier();  // covers hbuf zero + att_lds + xbuf staging

  // att: one f32x4 per 4 steps from LDS, 2 buffers, 8-step lead
  const float* paL = &att_lds[n * 204];
  f32x4 ab0 = *(const f32x4*)(paL + 0);  // t = 0..3
  f32x4 ab1 = *(const f32x4*)(paL + 4);  // t = 4..7

  if constexpr (DIRECT) {
    const short* pxt = px + (size_t)12 * 512;  // frags for step 3 (t+3 at t=0)
    for (int tb = 0; tb < T_; tb += 8) {       // 200 = 25 * 8
#pragma unroll
      for (int k = 0; k < 8; ++k) {
        const int t = tb + k;
        const int cur = k & 1, nxt = cur ^ 1;
        // h-frags for step t: issue reads first (recurrence-critical)
        short8 ha[4];
#pragma unroll
        for (int ks = 0; ks < 4; ++ks)
          ha[ks] = *(short8*)&hbuf[cur][n * 128 + ((ks * 4 + q) ^ (n & 7)) * 8];

        // x-side for step t+1 FIRST: register-only inputs, no lgkm dep —
        // the 12 MFMAs cover the ds_read(ha) latency after the barrier.
        {
          const short8 x0s = xp[nxt][0].s;
          xq[nxt][0] = MFMA(wf[0][0], x0s, bu4);
          xq[nxt][1] = MFMA(wf[2][0], x0s, br4);
          xq[nxt][2] = MFMA(wf[4][0], x0s, bxg4);
#pragma unroll
          for (int ks = 1; ks < 4; ++ks) {
            const short8 xs = xp[nxt][ks].s;
            xq[nxt][0] = MFMA(wf[0][ks], xs, xq[nxt][0]);
            xq[nxt][1] = MFMA(wf[2][ks], xs, xq[nxt][1]);
            xq[nxt][2] = MFMA(wf[4][ks], xs, xq[nxt][2]);
          }
        }

        // h-side chains C-SEEDED with x-accumulators (u,r) / bias (g)
        f32x4 ahu = MFMA(wf[1][0], ha[0], xq[cur][0]);
        f32x4 ahr = MFMA(wf[3][0], ha[0], xq[cur][1]);
        f32x4 ahg = MFMA(wf[5][0], ha[0], bhg4);
#pragma unroll
        for (int ks = 1; ks < 4; ++ks) {
          ahu = MFMA(wf[1][ks], ha[ks], ahu);
          ahr = MFMA(wf[3][ks], ha[ks], ahr);
          ahg = MFMA(wf[5][ks], ha[ks], ahg);
        }

        // reload slot nxt with frags for step t+3 (pure pointer walk)
#pragma unroll
        for (int ks = 0; ks < 4; ++ks)
          xp[nxt][ks].u = *(const uint4*)(pxt + (size_t)(k * 4 + ks) * 512);

        // att for this step (masks fold; reloads from LDS, aligned)
        const float at = ((k >> 2) & 1) ? ab1[k & 3] : ab0[k & 3];
        if (k == 3) ab0 = *(const f32x4*)(paL + ((t + 5 <= T_ - 4) ? t + 5 : T_ - 4));
        if (k == 7) ab1 = *(const f32x4*)(paL + ((t + 5 <= T_ - 4) ? t + 5 : T_ - 4));

        // gates: pre-activations complete and exp2-prescaled
        float hn[4];
#pragma unroll
        for (int r = 0; r < 4; ++r) {
          const float uu = at * rcp_f(1.0f + exp2_f(-ahu[r]));
          const float rr = rcp_f(1.0f + exp2_f(-ahr[r]));
          const float sg = xq[cur][2][r] + rr * ahg[r];
          const float g = 2.0f * rcp_f(1.0f + exp2_f(-sg)) - 1.0f;
          hn[r] = hreg[r] + uu * (g - hreg[r]);
          hreg[r] = hn[r];
        }

        // single 8B LDS write: 4 consecutive bf16 cols of row n (v_perm packs)
        uint2 up;
        up.x = pack2bf_trunc(hn[0], hn[1]);
        up.y = pack2bf_trunc(hn[2], hn[3]);
        *(uint2*)&hbuf[nxt][wri] = up;
        ck_barrier();
      }
      pxt += (size_t)8 * 4 * 512;
    }
  } else {
    // fallback: LDS-staged x path
#pragma unroll 2
    for (int t = 0; t < T_; ++t) {
      const int cur = t & 1, nxt = cur ^ 1;
      short8 ha[4];
#pragma unroll
      for (int ks = 0; ks < 4; ++ks)
        ha[ks] = *(short8*)&hbuf[cur][n * 128 + ((ks * 4 + q) ^ (n & 7)) * 8];
      short8 xa[4];
#pragma unroll
      for (int ks = 0; ks < 4; ++ks)
        xa[ks] = *(short8*)&xbuf[cur][n * 128 + ((ks * 4 + q) ^ (n & 7)) * 8];
      f32x4 xu_a = MFMA(wf[0][0], xa[0], bu4);
      f32x4 xr_a = MFMA(wf[2][0], xa[0], br4);
      f32x4 xg_a = MFMA(wf[4][0], xa[0], bxg4);
#pragma unroll
      for (int ks = 1; ks < 4; ++ks) {
        xu_a = MFMA(wf[0][ks], xa[ks], xu_a);
        xr_a = MFMA(wf[2][ks], xa[ks], xr_a);
        xg_a = MFMA(wf[4][ks], xa[ks], xg_a);
      }
      f32x4 ahu = MFMA(wf[1][0], ha[0], xu_a);
      f32x4 ahr = MFMA(wf[3][0], ha[0], xr_a);
      f32x4 ahg = MFMA(wf[5][0], ha[0], bhg4);
#pragma unroll
      for (int ks = 1; ks < 4; ++ks) {
        ahu = MFMA(wf[1][ks], ha[ks], ahu);
        ahr = MFMA(wf[3][ks], ha[ks], ahr);
        ahg = MFMA(wf[5][ks], ha[ks], ahg);
      }
      const int tp = (t + 2 < T_) ? t + 2 : T_ - 1;
      const float at = ((t >> 2) & 1) ? ab1[t & 3] : ab0[t & 3];
      if ((t & 7) == 3) ab0 = *(const f32x4*)(paL + ((t + 5 <= T_ - 4) ? t + 5 : T_ - 4));
      if ((t & 7) == 7) ab1 = *(const f32x4*)(paL + ((t + 5 <= T_ - 4) ? t + 5 : T_ - 4));
      float hn[4];
#pragma unroll
      for (int r = 0; r < 4; ++r) {
        const float uu = at * rcp_f(1.0f + exp2_f(-ahu[r]));
        const float rr = rcp_f(1.0f + exp2_f(-ahr[r]));
        const float sg = xg_a[r] + rr * ahg[r];
        const float g = 2.0f * rcp_f(1.0f + exp2_f(-sg)) - 1.0f;
        hn[r] = hreg[r] + uu * (g - hreg[r]);
        hreg[r] = hn[r];
      }
      uint2 up;
      up.x = pack2bf_trunc(hn[0], hn[1]);
      up.y = pack2bf_trunc(hn[2], hn[3]);
      *(uint2*)&hbuf[nxt][wri] = up;
      uint2 u;
      u.x = pack2bf_rne(xnext.x, xnext.y);
      u.y = pack2bf_rne(xnext.z, xnext.w);
      *(uint2*)&xbuf[nxt][xpos] = u;  // stage x(t+1)
      xnext = *(const float4*)(hrow + (size_t)tp * H_);
      ck_barrier();
    }
  }

  // final h store (hreg holds h(T-1))
  f32x4 hv = {hreg[0], hreg[1], hreg[2], hreg[3]};
  *(f32x4*)(h_out + (size_t)(r0 + n) * H_ + ob) = hv;
}

// ---------------------------------------------------------------------------
// K_D: out = [h | targets[:,0]] @ ln2_w^T + ln2_b (fp32)
// v2: 4 batch rows per block (grid 256): each ln2_w fragment loaded once
// per block serves 4 rows (register reuse; L2 weight traffic 134->33 MB).
// 4 independent acc chains give the ILP to cover load latency at 1 blk/CU.
// ---------------------------------------------------------------------------
__global__ __launch_bounds__(256, 4) void final_kernel(
    const float* __restrict__ tgt, const float* __restrict__ hfin,
    const float* __restrict__ w, const float* __restrict__ bias,
    float* __restrict__ out) {
  const int b4 = blockIdx.x * 4, tid = threadIdx.x;
  const int o = tid >> 1, half = tid & 1;
  const float* wrow = w + o * 256 + half * 128;
  const float* s0 = half ? (tgt + (size_t)(b4 + 0) * (T_ * H_)) : (hfin + (size_t)(b4 + 0) * H_);
  const float* s1 = half ? (tgt + (size_t)(b4 + 1) * (T_ * H_)) : (hfin + (size_t)(b4 + 1) * H_);
  const float* s2 = half ? (tgt + (size_t)(b4 + 2) * (T_ * H_)) : (hfin + (size_t)(b4 + 2) * H_);
  const float* s3 = half ? (tgt + (size_t)(b4 + 3) * (T_ * H_)) : (hfin + (size_t)(b4 + 3) * H_);
  float a0 = 0.0f, a1 = 0.0f, a2 = 0.0f, a3 = 0.0f;
#pragma unroll 8
  for (int k = 0; k < 128; k += 4) {
    const float4 wv = *(const float4*)(wrow + k);
    float4 v;
    v = *(const float4*)(s0 + k);
    a0 += v.x * wv.x + v.y * wv.y + v.z * wv.z + v.w * wv.w;
    v = *(const float4*)(s1 + k);
    a1 += v.x * wv.x + v.y * wv.y + v.z * wv.z + v.w * wv.w;
    v = *(const float4*)(s2 + k);
    a2 += v.x * wv.x + v.y * wv.y + v.z * wv.z + v.w * wv.w;
    v = *(const float4*)(s3 + k);
    a3 += v.x * wv.x + v.y * wv.y + v.z * wv.z + v.w * wv.w;
  }
  a0 += __shfl_xor(a0, 1);
  a1 += __shfl_xor(a1, 1);
  a2 += __shfl_xor(a2, 1);
  a3 += __shfl_xor(a3, 1);
  if (half == 0) {
    const float bo = bias[o];
    out[(size_t)(b4 + 0) * H_ + o] = a0 + bo;
    out[(size_t)(b4 + 1) * H_ + o] = a1 + bo;
    out[(size_t)(b4 + 2) * H_ + o] = a2 + bo;
    out[(size_t)(b4 + 3) * H_ + o] = a3 + bo;
  }
}

extern "C" void kernel_launch(void* const* d_in, const int* in_sizes, int n_in,
                              void* d_out, int out_size, void* d_ws, size_t ws_size,
                              hipStream_t stream) {
  const float* targets = (const float*)d_in[0];
  const float* history = (const float*)d_in[1];
  const float* W_w = (const float*)d_in[2];
  const float* W_b = (const float*)d_in[3];
  const float* xu_w = (const float*)d_in[4];
  const float* xu_b = (const float*)d_in[5];
  const float* hu_w = (const float*)d_in[6];
  const float* hu_b = (const float*)d_in[7];
  const float* xr_w = (const float*)d_in[8];
  const float* xr_b = (const float*)d_in[9];
  const float* hr_w = (const float*)d_in[10];
  const float* hr_b = (const float*)d_in[11];
  const float* xg_w = (const float*)d_in[12];
  const float* xg_b = (const float*)d_in[13];
  const float* hg_w = (const float*)d_in[14];
  const float* hg_b = (const float*)d_in[15];
  const float* ln2_w = (const float*)d_in[16];
  const float* ln2_b = (const float*)d_in[17];
  float* out = (float*)d_out;

  float* att = (float*)d_ws;            // [B,T] f32 (raw scores; softmax fused in scan)
  float* hfin = att + (size_t)B_ * T_;  // [B,H] f32
  const size_t fixed = (size_t)B_ * T_ * 4 + (size_t)B_ * H_ * 4;
  const size_t histbf_bytes = (size_t)64 * TSTR * 4 * 512 * 2;  // 53.5 MB
  short* histbf = (ws_size >= fixed + histbf_bytes)
                      ? (short*)((char*)d_ws + fixed)
                      : nullptr;

  proj_scores_kernel<<<dim3(13, 64), dim3(512), 0, stream>>>(
      targets, history, W_w, W_b, att, histbf);
  if (histbf) {
    scan3_kernel<true><<<dim3(64), dim3(512), 0, stream>>>(
        history, xu_w, xu_b, hu_w, hu_b, xr_w, xr_b, hr_w, hr_b,
        xg_w, xg_b, hg_w, hg_b, att, histbf, hfin);
  } else {
    scan3_kernel<false><<<dim3(64), dim3(512), 0, stream>>>(
        history, xu_w, xu_b, hu_w, hu_b, xr_w, xr_b, hr_w, hr_b,
        xg_w, xg_b, hg_w, hg_b, att, histbf, hfin);
  }
  final_kernel<<<dim3(B_ / 4), dim3(256), 0, stream>>>(targets, hfin, ln2_w, ln2_b, out);
}